// Round 17
// baseline (1418.746 us; speedup 1.0000x reference)
//
#include <hip/hip_runtime.h>

typedef short bf16x8 __attribute__((ext_vector_type(8)));
typedef float f32x4 __attribute__((ext_vector_type(4)));
typedef unsigned short us;

#define BN_EPS 1e-3f

// fp32 -> bf16 round-to-nearest-even (no NaN inputs in this net)
static __device__ __forceinline__ us f2bs(float x) {
  unsigned int u = __builtin_bit_cast(unsigned int, x);
  unsigned int r = (u + 0x7FFFu + ((u >> 16) & 1u)) >> 16;
  return (us)r;
}
static __device__ __forceinline__ float b2f(us v) {
  unsigned int u = (unsigned int)v << 16;
  return __builtin_bit_cast(float, u);
}

// async global->LDS, 16B per lane; LDS dest is wave-uniform base + lane*16.
static __device__ __forceinline__ void gl_lds16(const us* g, us* l) {
  __builtin_amdgcn_global_load_lds(
      (const __attribute__((address_space(1))) void*)g,
      (__attribute__((address_space(3))) void*)l, 16, 0, 0);
}

// ---------------- transpose + fp32->bf16: src [K,N] f32 -> dst [N,K] bf16 ----
__global__ __launch_bounds__(256) void transpose_bf16(
    const float* __restrict__ src, us* __restrict__ dst, int K, int N,
    long sstride, long dstride) {
  long sbs = (long)blockIdx.z * sstride;
  long sbd = (long)blockIdx.z * dstride;
  __shared__ float tile[32][33];
  int tx = threadIdx.x & 31, ty = threadIdx.x >> 5;  // 32 x 8
  int k0 = blockIdx.x * 32, n0 = blockIdx.y * 32;
  for (int i = 0; i < 32; i += 8)
    tile[ty + i][tx] = src[sbs + (long)(k0 + ty + i) * N + n0 + tx];
  __syncthreads();
  for (int i = 0; i < 32; i += 8)
    dst[sbd + (long)(n0 + ty + i) * K + k0 + tx] = f2bs(tile[tx][ty + i]);
}

// ---------------- embedding: hb = bf16(state @ Wemb + bemb + pes) -----------
__global__ __launch_bounds__(256) void embed_kernel(
    const float* __restrict__ state, const float* __restrict__ Wemb,
    const float* __restrict__ bemb, const float* __restrict__ pes,
    us* __restrict__ hb) {
  int t = threadIdx.x;
  int row0 = blockIdx.x * 8;
  __shared__ float st[8][64];
  {
    int i = t;
    st[i >> 6][i & 63] = state[(long)row0 * 64 + i];
    i += 256;
    st[i >> 6][i & 63] = state[(long)row0 * 64 + i];
  }
  __syncthreads();
  int c0 = t, c1 = t + 256;
  float acc0[8], acc1[8];
#pragma unroll
  for (int r = 0; r < 8; ++r) { acc0[r] = 0.f; acc1[r] = 0.f; }
  for (int kk = 0; kk < 64; ++kk) {
    float w0 = Wemb[kk * 512 + c0], w1 = Wemb[kk * 512 + c1];
#pragma unroll
    for (int r = 0; r < 8; ++r) {
      acc0[r] += st[r][kk] * w0;
      acc1[r] += st[r][kk] * w1;
    }
  }
  float be0 = bemb[c0], be1 = bemb[c1];
#pragma unroll
  for (int r = 0; r < 8; ++r) {
    int row = row0 + r, s = row & 255;
    hb[(long)row * 512 + c0] = f2bs(acc0[r] + be0 + pes[(long)s * 512 + c0]);
    hb[(long)row * 512 + c1] = f2bs(acc1[r] + be1 + pes[(long)s * 512 + c1]);
  }
}

enum { EPI_QKV = 0, EPI_RESID_BF16 = 1, EPI_RELU_BF16 = 2, EPI_FFN2_BF16 = 3,
       EPI_FEAT = 4 };

// =============== 8-wave 256x128 pipelined GEMM (all main GEMMs) =============
// Ring of 4 x 24KB slots; 3 gl_lds/chunk -> vmcnt(6)/3/0; waves 4Mx2N.
// Grids (all multiples of 256 blocks = balanced rounds at 1 block/CU):
//   QKV (64,12)=768, Wo (64,4)=256, FFN1 (64,16)=1024 (R17), FFN2 (64,4)=256.
template <int EPI>
__global__ __launch_bounds__(512, 2) void gemm256x128(
    const us* __restrict__ A, int lda, const us* __restrict__ Bt, int ldb,
    us* __restrict__ Cout, us* __restrict__ C2, us* __restrict__ C3, int ldc,
    const float* __restrict__ bias, const us* __restrict__ resid,
    float* __restrict__ gsum, float* __restrict__ gsumsq,
    const float* __restrict__ gamma, const float* __restrict__ beta, int K) {
  const int tid = threadIdx.x;
  const int w = tid >> 6, l = tid & 63;
  const int wr = w >> 1, wc = w & 1;
  const int lr = l & 15, lh = l >> 4;
  const long m0 = (long)blockIdx.x * 256;
  const long n0 = (long)blockIdx.y * 128;
  const int KC = K >> 5;
  __shared__ __align__(16) us sh[4 * 12288];  // 4 slots x 24KB = 96KB
  const int o = tid * 16;
  const int lg = o ^ ((o >> 2) & 0x30);
  const int sr = lg >> 6;
  const int sc = (lg & 63) >> 1;
  const int pb = lr * 32 + ((lh * 8) ^ ((lr & 3) << 3));
  const us* Asl = sh + wr * 2048 + pb;          // A: [0, 8192) us
  const us* Bsl = sh + 8192 + wc * 2048 + pb;   // B: [8192, 12288) us

  for (int j = 0; j < 3; ++j) {
    us* slot = sh + j * 12288;
    gl_lds16(A + (m0 + sr) * lda + j * 32 + sc, slot + tid * 8);
    gl_lds16(A + (m0 + 128 + sr) * lda + j * 32 + sc, slot + 4096 + tid * 8);
    gl_lds16(Bt + (n0 + sr) * ldb + j * 32 + sc, slot + 8192 + tid * 8);
  }
  asm volatile("s_waitcnt vmcnt(6)" ::: "memory");  // chunk 0's 3 loads done
  __builtin_amdgcn_s_barrier();

  f32x4 acc[4][4] = {};
  for (int c = 0; c < KC; ++c) {
    const int soff = (c & 3) * 12288;
    const bool st = (c + 3) < KC;
    us* nslot = sh + ((c + 3) & 3) * 12288;
    const int nk = (c + 3) * 32;
    if (st) {
      gl_lds16(A + (m0 + sr) * lda + nk + sc, nslot + tid * 8);
      gl_lds16(A + (m0 + 128 + sr) * lda + nk + sc, nslot + 4096 + tid * 8);
    }
    bf16x8 bfr[4], af[2];
#pragma unroll
    for (int ni = 0; ni < 4; ++ni)
      bfr[ni] = *(const bf16x8*)(Bsl + soff + ni * 512);
#pragma unroll
    for (int mi = 0; mi < 2; ++mi)
      af[mi] = *(const bf16x8*)(Asl + soff + mi * 512);
    __builtin_amdgcn_s_barrier();
    __builtin_amdgcn_s_setprio(1);
#pragma unroll
    for (int mi = 0; mi < 2; ++mi)
#pragma unroll
      for (int ni = 0; ni < 4; ++ni)
        acc[mi][ni] = __builtin_amdgcn_mfma_f32_16x16x32_bf16(
            af[mi], bfr[ni], acc[mi][ni], 0, 0, 0);
    __builtin_amdgcn_s_setprio(0);
    __builtin_amdgcn_s_barrier();
    if (st) {
      gl_lds16(Bt + (n0 + sr) * ldb + nk + sc, nslot + 8192 + tid * 8);
    }
#pragma unroll
    for (int mi = 0; mi < 2; ++mi)
      af[mi] = *(const bf16x8*)(Asl + soff + (mi + 2) * 512);
    __builtin_amdgcn_s_barrier();
    __builtin_amdgcn_s_setprio(1);
#pragma unroll
    for (int mi = 0; mi < 2; ++mi)
#pragma unroll
      for (int ni = 0; ni < 4; ++ni)
        acc[mi + 2][ni] = __builtin_amdgcn_mfma_f32_16x16x32_bf16(
            af[mi], bfr[ni], acc[mi + 2][ni], 0, 0, 0);
    __builtin_amdgcn_s_setprio(0);
    if (c < KC - 3)
      asm volatile("s_waitcnt vmcnt(6)" ::: "memory");
    else if (c == KC - 3)
      asm volatile("s_waitcnt vmcnt(3)" ::: "memory");
    else if (c == KC - 2)
      asm volatile("s_waitcnt vmcnt(0)" ::: "memory");
    __builtin_amdgcn_s_barrier();
  }

  if constexpr (EPI == EPI_QKV) {
    const int seg = (int)(n0 >> 9);  // block-uniform
    const int nc0 = (int)(n0 & 511);
    if (seg == 2) {
      // V^T: 4 consecutive s-rows contiguous -> ushort4 register path
#pragma unroll
      for (int mi = 0; mi < 4; ++mi)
#pragma unroll
        for (int ni = 0; ni < 4; ++ni) {
          const int segc = nc0 + wc * 64 + ni * 16 + lr;
          const float bv_ = beta[segc];
          ushort4 pv;
#pragma unroll
          for (int q_ = 0; q_ < 4; ++q_)
            ((us*)&pv)[q_] = f2bs(acc[mi][ni][q_] + bv_);
          const long row0g = m0 + wr * 64 + mi * 16 + lh * 4;
          const long oo =
              (((row0g >> 8) * 8 + (segc >> 6)) * 64 + (segc & 63)) * 256 +
              (row0g & 255);
          *(ushort4*)&C3[oo] = pv;
        }
    } else {
      // q/k: stage C-tile [256][128] in sh (64KB <= 96KB), coalesced write
#pragma unroll
      for (int mi = 0; mi < 4; ++mi)
#pragma unroll
        for (int ni = 0; ni < 4; ++ni) {
          const int cl = wc * 64 + ni * 16 + lr;
          const float bv_ = seg == 0 ? bias[nc0 + cl] : gamma[nc0 + cl];
#pragma unroll
          for (int q_ = 0; q_ < 4; ++q_) {
            const int rl = wr * 64 + mi * 16 + lh * 4 + q_;
            sh[rl * 128 + cl] = f2bs(acc[mi][ni][q_] + bv_);
          }
        }
      asm volatile("s_waitcnt lgkmcnt(0)" ::: "memory");
      __builtin_amdgcn_s_barrier();
      us* dstp = seg == 0 ? Cout : C2;
      for (int i = tid; i < 4096; i += 512) {
        const int idx = i * 8;
        const int row = idx >> 7, col = idx & 127;
        *(uint4*)&dstp[(m0 + row) * 512 + nc0 + col] = *(uint4*)&sh[idx];
      }
    }
  } else if constexpr (EPI == EPI_RESID_BF16) {
    // y = acc + bias + resid; fused BN-stats (shfl reduce + global atomics)
    float cs[4] = {}, cq[4] = {};
#pragma unroll
    for (int mi = 0; mi < 4; ++mi)
#pragma unroll
      for (int ni = 0; ni < 4; ++ni) {
        const int cl = wc * 64 + ni * 16 + lr;
        const int col = (int)n0 + cl;
        const float bv_ = bias[col];
#pragma unroll
        for (int q_ = 0; q_ < 4; ++q_) {
          const int rl = wr * 64 + mi * 16 + lh * 4 + q_;
          float v = acc[mi][ni][q_] + bv_ + b2f(resid[(m0 + rl) * ldc + col]);
          cs[ni] += v;
          cq[ni] += v * v;
          sh[rl * 128 + cl] = f2bs(v);
        }
      }
#pragma unroll
    for (int ni = 0; ni < 4; ++ni) {
      float s = cs[ni], qv = cq[ni];
      s += __shfl_xor(s, 16);
      qv += __shfl_xor(qv, 16);
      s += __shfl_xor(s, 32);
      qv += __shfl_xor(qv, 32);
      if (lh == 0) {
        const int col = (int)n0 + wc * 64 + ni * 16 + lr;
        atomicAdd(&gsum[col], s);
        atomicAdd(&gsumsq[col], qv);
      }
    }
    asm volatile("s_waitcnt lgkmcnt(0)" ::: "memory");
    __builtin_amdgcn_s_barrier();
    for (int i = tid; i < 4096; i += 512) {
      const int idx = i * 8;
      const int row = idx >> 7, col = idx & 127;
      *(uint4*)&Cout[(m0 + row) * ldc + n0 + col] = *(uint4*)&sh[idx];
    }
  } else if constexpr (EPI == EPI_RELU_BF16) {
    // f1 = relu(acc + bias), bf16 staged coalesced write (FFN1, R17)
#pragma unroll
    for (int mi = 0; mi < 4; ++mi)
#pragma unroll
      for (int ni = 0; ni < 4; ++ni) {
        const int cl = wc * 64 + ni * 16 + lr;
        const float bv_ = bias[(int)n0 + cl];
#pragma unroll
        for (int q_ = 0; q_ < 4; ++q_) {
          const int rl = wr * 64 + mi * 16 + lh * 4 + q_;
          sh[rl * 128 + cl] = f2bs(fmaxf(acc[mi][ni][q_] + bv_, 0.f));
        }
      }
    asm volatile("s_waitcnt lgkmcnt(0)" ::: "memory");
    __builtin_amdgcn_s_barrier();
    for (int i = tid; i < 4096; i += 512) {
      const int idx = i * 8;
      const int row = idx >> 7, col = idx & 127;
      *(uint4*)&Cout[(m0 + row) * ldc + n0 + col] = *(uint4*)&sh[idx];
    }
  } else {  // EPI_FFN2_BF16: z = (a*y+b) + acc + bias
#pragma unroll
    for (int mi = 0; mi < 4; ++mi)
#pragma unroll
      for (int ni = 0; ni < 4; ++ni) {
        const int cl = wc * 64 + ni * 16 + lr;
        const int col = (int)n0 + cl;
        const float bv_ = bias[col];
        const float aa = gsum[col], bb2 = gsumsq[col];
#pragma unroll
        for (int q_ = 0; q_ < 4; ++q_) {
          const int rl = wr * 64 + mi * 16 + lh * 4 + q_;
          float ybn = b2f(resid[(m0 + rl) * ldc + col]) * aa + bb2;
          sh[rl * 128 + cl] = f2bs(ybn + acc[mi][ni][q_] + bv_);
        }
      }
    asm volatile("s_waitcnt lgkmcnt(0)" ::: "memory");
    __builtin_amdgcn_s_barrier();
    for (int i = tid; i < 4096; i += 512) {
      const int idx = i * 8;
      const int row = idx >> 7, col = idx & 127;
      *(uint4*)&Cout[(m0 + row) * ldc + n0 + col] = *(uint4*)&sh[idx];
    }
  }
}

// ---------------- generic bf16 MFMA GEMM (feat split-K only) ----------------
template <int BM, int BN, int WM, int WN, int EPI>
__global__ __launch_bounds__((BM / WM) * (BN / WN) * 64)
void gemm_bt(const us* __restrict__ A, int lda, long batchA,
             const us* __restrict__ Bt, int ldb, long batchB,
             void* __restrict__ Cout, int ldc, int K) {
  constexpr int WCols = BN / WN;
  constexpr int NT = (BM / WM) * (BN / WN) * 64;
  constexpr int NW = NT / 64;
  constexpr int MI = WM / 16, NI = WN / 16;
  constexpr int LA = BM / 8;
  constexpr int LB = BN / 8;
  const int tid = threadIdx.x;
  const int w = tid >> 6, l = tid & 63;
  const int wr = w / WCols, wc = w % WCols;
  const int lr = l & 15, lh = l >> 4;
  const int z = blockIdx.z;
  const long m0 = (long)blockIdx.x * BM;
  const long n0 = (long)blockIdx.y * BN;
  A += (long)z * batchA;
  Bt += (long)z * batchB;
  __shared__ __align__(16) us smem[BM * 64 + BN * 64];
  us* Asm = smem;
  us* Bsm = smem + BM * 64;
  const int srow = l >> 3, scol = (l & 7) << 3;
  f32x4 acc[MI][NI] = {};
  for (int kt = 0; kt < K; kt += 64) {
    __syncthreads();
    for (int j = w; j < LA; j += NW) {
      int rb = j * 8;
      gl_lds16(A + (m0 + rb + srow) * lda + kt + scol, Asm + rb * 64);
    }
    for (int j = w; j < LB; j += NW) {
      int rb = j * 8;
      gl_lds16(Bt + (n0 + rb + srow) * ldb + kt + scol, Bsm + rb * 64);
    }
    asm volatile("s_waitcnt vmcnt(0)" ::: "memory");
    __syncthreads();
#pragma unroll
    for (int kk = 0; kk < 64; kk += 32) {
      bf16x8 af[MI], bfr[NI];
#pragma unroll
      for (int mi = 0; mi < MI; ++mi)
        af[mi] = *(const bf16x8*)&Asm[(wr * WM + mi * 16 + lr) * 64 + kk + lh * 8];
#pragma unroll
      for (int ni = 0; ni < NI; ++ni)
        bfr[ni] = *(const bf16x8*)&Bsm[(wc * WN + ni * 16 + lr) * 64 + kk + lh * 8];
#pragma unroll
      for (int mi = 0; mi < MI; ++mi)
#pragma unroll
        for (int ni = 0; ni < NI; ++ni)
          acc[mi][ni] = __builtin_amdgcn_mfma_f32_16x16x32_bf16(
              af[mi], bfr[ni], acc[mi][ni], 0, 0, 0);
    }
  }
#pragma unroll
  for (int mi = 0; mi < MI; ++mi) {
#pragma unroll
    for (int ni = 0; ni < NI; ++ni) {
      const int col = (int)n0 + wc * WN + ni * 16 + lr;
#pragma unroll
      for (int q_ = 0; q_ < 4; ++q_) {
        const long row = m0 + wr * WM + mi * 16 + lh * 4 + q_;
        atomicAdd(&((float*)Cout)[row * ldc + col], acc[mi][ni][q_]);
      }
    }
  }
}

// ---------------- fused attention v3: K/V cached in LDS per (b,h) -----------
__global__ __launch_bounds__(512) void attn_kernel(
    const us* __restrict__ q, const us* __restrict__ k,
    const us* __restrict__ vt, us* __restrict__ ctx) {
  const int z = blockIdx.x;  // b*8+h
  const int b = z >> 3, hh = z & 7;
  const long qkBase = (long)b * 131072 + hh * 64;
  const int tid = threadIdx.x, w = tid >> 6, l = tid & 63;
  const int lr = l & 15, lh = l >> 4;
  const int hf = w >> 2, w2 = w & 3;  // wave-group (tile) and sub-wave
  const int qr = (w2 >> 1) * 16, qc = (w2 & 1) * 32;
  __shared__ __align__(16) us Kf[256][72];   // 36.9 KB
  __shared__ __align__(16) us Vf[64][264];   // 33.8 KB
  __shared__ __align__(16) us Qs[2][32][72];
  __shared__ __align__(16) us Pb[2][32][264];
  __shared__ float fred[2][32][2];
  const us* vb = vt + (long)z * 16384;
  for (int i = tid; i < 2048; i += 512) {
    int r = i >> 3, c = (i & 7) << 3;
    *(uint4*)&Kf[r][c] = *(const uint4*)(k + qkBase + (long)r * 512 + c);
  }
  for (int i = tid; i < 2048; i += 512) {
    int r = i >> 5, c = (i & 31) << 3;
    *(uint4*)&Vf[r][c] = *(const uint4*)(vb + (long)r * 256 + c);
  }
  const int th = tid & 255, qhf = tid >> 8;
  const int qlr = th >> 3, qlc = (th & 7) << 3;
  __syncthreads();

  for (int qi = 0; qi < 4; ++qi) {
    const int qbl = qi * 2 + qhf;
    *(uint4*)&Qs[qhf][qlr][qlc] =
        *(const uint4*)(q + qkBase + (long)(qbl * 32 + qlr) * 512 + qlc);
    __syncthreads();
    const int myqb = qi * 2 + hf;
    f32x4 sacc[4][2] = {};
#pragma unroll
    for (int skb = 0; skb < 4; ++skb)
#pragma unroll
      for (int kh = 0; kh < 2; ++kh) {
        bf16x8 aq = *(const bf16x8*)&Qs[hf][qr + lr][kh * 32 + lh * 8];
#pragma unroll
        for (int ni = 0; ni < 2; ++ni) {
          bf16x8 bkk =
              *(const bf16x8*)&Kf[skb * 64 + qc + ni * 16 + lr][kh * 32 + lh * 8];
          sacc[skb][ni] = __builtin_amdgcn_mfma_f32_16x16x32_bf16(
              aq, bkk, sacc[skb][ni], 0, 0, 0);
        }
      }
    float m0[4] = {-1e30f, -1e30f, -1e30f, -1e30f};
#pragma unroll
    for (int skb = 0; skb < 4; ++skb)
#pragma unroll
      for (int ni = 0; ni < 2; ++ni)
#pragma unroll
        for (int q_ = 0; q_ < 4; ++q_) {
          float v = sacc[skb][ni][q_] * 0.125f;
          sacc[skb][ni][q_] = v;
          m0[q_] = fmaxf(m0[q_], v);
        }
#pragma unroll
    for (int off = 1; off < 16; off <<= 1)
#pragma unroll
      for (int q_ = 0; q_ < 4; ++q_)
        m0[q_] = fmaxf(m0[q_], __shfl_xor(m0[q_], off));
    if (lr == 0) {
#pragma unroll
      for (int q_ = 0; q_ < 4; ++q_)
        fred[hf][qr + lh * 4 + q_][w2 & 1] = m0[q_];
    }
    __syncthreads();
#pragma unroll
    for (int q_ = 0; q_ < 4; ++q_) {
      int row = qr + lh * 4 + q_;
      m0[q_] = fmaxf(fred[hf][row][0], fred[hf][row][1]);
    }
    float s0[4] = {0.f, 0.f, 0.f, 0.f};
#pragma unroll
    for (int skb = 0; skb < 4; ++skb)
#pragma unroll
      for (int ni = 0; ni < 2; ++ni)
#pragma unroll
        for (int q_ = 0; q_ < 4; ++q_) {
          float e = __expf(sacc[skb][ni][q_] - m0[q_]);
          sacc[skb][ni][q_] = e;
          s0[q_] += e;
        }
#pragma unroll
    for (int off = 1; off < 16; off <<= 1)
#pragma unroll
      for (int q_ = 0; q_ < 4; ++q_) s0[q_] += __shfl_xor(s0[q_], off);
    __syncthreads();
    if (lr == 0) {
#pragma unroll
      for (int q_ = 0; q_ < 4; ++q_)
        fred[hf][qr + lh * 4 + q_][w2 & 1] = s0[q_];
    }
    __syncthreads();
#pragma unroll
    for (int q_ = 0; q_ < 4; ++q_) {
      int row = qr + lh * 4 + q_;
      s0[q_] = 1.f / (fred[hf][row][0] + fred[hf][row][1]);
    }
#pragma unroll
    for (int skb = 0; skb < 4; ++skb)
#pragma unroll
      for (int ni = 0; ni < 2; ++ni)
#pragma unroll
        for (int q_ = 0; q_ < 4; ++q_)
          Pb[hf][qr + lh * 4 + q_][skb * 64 + qc + ni * 16 + lr] =
              f2bs(sacc[skb][ni][q_] * s0[q_]);
    __syncthreads();
    f32x4 pacc[2] = {};
#pragma unroll
    for (int kc = 0; kc < 256; kc += 64)
#pragma unroll
      for (int kh = 0; kh < 2; ++kh) {
        bf16x8 ap = *(const bf16x8*)&Pb[hf][qr + lr][kc + kh * 32 + lh * 8];
#pragma unroll
        for (int ni = 0; ni < 2; ++ni) {
          bf16x8 bv2 =
              *(const bf16x8*)&Vf[qc + ni * 16 + lr][kc + kh * 32 + lh * 8];
          pacc[ni] = __builtin_amdgcn_mfma_f32_16x16x32_bf16(
              ap, bv2, pacc[ni], 0, 0, 0);
        }
      }
    const long cb2 = ((long)(b * 256 + myqb * 32)) * 512 + hh * 64;
#pragma unroll
    for (int ni = 0; ni < 2; ++ni)
#pragma unroll
      for (int q_ = 0; q_ < 4; ++q_) {
        int row = qr + lh * 4 + q_;
        int col = qc + ni * 16 + lr;
        ctx[cb2 + (long)row * 512 + col] = f2bs(pacc[ni][q_]);
      }
    __syncthreads();
  }
}

// bn_coef: gsum/gsumsq -> (a, b) in place
__global__ void bn_coef(float* __restrict__ gsum, float* __restrict__ gsumsq,
                        const float* __restrict__ gamma,
                        const float* __restrict__ beta) {
  int c = blockIdx.x * 256 + threadIdx.x;
  if (c < 512) {
    const float invN = 1.f / 16384.f;
    float mu = gsum[c] * invN;
    float var = gsumsq[c] * invN - mu * mu;
    float a = gamma[c] * rsqrtf(var + BN_EPS);
    float b = beta[c] - mu * a;
    gsum[c] = a;
    gsumsq[c] = b;
  }
}

// fold_w1: W1s[n][k] = bf16(a_k*W1T[n][k]); bias1f[n] = b1[n] + sum_k b_k*W1T
__global__ __launch_bounds__(256) void fold_w1(
    const us* __restrict__ W1T, const float* __restrict__ aa,
    const float* __restrict__ bb, const float* __restrict__ b1,
    us* __restrict__ W1s, float* __restrict__ bias1f) {
  int n = blockIdx.x * 4 + (threadIdx.x >> 6);
  int l = threadIdx.x & 63;
  int k0 = l * 8;
  const us* row = W1T + (long)n * 512;
  us tmp[8], outv[8];
  *(uint4*)tmp = *(const uint4*)(row + k0);
  float dot = 0.f;
#pragma unroll
  for (int j = 0; j < 8; ++j) {
    float wv = b2f(tmp[j]);
    dot += bb[k0 + j] * wv;
    outv[j] = f2bs(aa[k0 + j] * wv);
  }
  *(uint4*)(W1s + (long)n * 512 + k0) = *(uint4*)outv;
  for (int off = 32; off >= 1; off >>= 1) dot += __shfl_down(dot, off);
  if (l == 0) bias1f[n] = b1[n] + dot;
}

// ---------------- LayerNorm per row: zbf (bf16) -> hb (bf16) ----------------
// block 0 also zeroes gsum/gsumsq for the next layer's fused BN stats.
__global__ __launch_bounds__(128) void ln_kernel(
    const us* __restrict__ zin, const float* __restrict__ g,
    const float* __restrict__ b, us* __restrict__ hb,
    float* __restrict__ gsum, float* __restrict__ gsumsq) {
  int r = blockIdx.x, t = threadIdx.x;
  if (r == 0) {
    for (int i = t; i < 512; i += 128) {
      gsum[i] = 0.f;
      gsumsq[i] = 0.f;
    }
  }
  const us* zr = zin + (long)r * 512;
  ushort4 vz = *(const ushort4*)(zr + t * 4);
  float v0 = b2f(((us*)&vz)[0]), v1 = b2f(((us*)&vz)[1]);
  float v2 = b2f(((us*)&vz)[2]), v3 = b2f(((us*)&vz)[3]);
  float s = v0 + v1 + v2 + v3;
  float qs = v0 * v0 + v1 * v1 + v2 * v2 + v3 * v3;
  for (int off = 32; off >= 1; off >>= 1) {
    s += __shfl_down(s, off);
    qs += __shfl_down(qs, off);
  }
  __shared__ float ls[2], lq[2];
  if ((t & 63) == 0) {
    ls[t >> 6] = s;
    lq[t >> 6] = qs;
  }
  __syncthreads();
  float mu = (ls[0] + ls[1]) * (1.f / 512.f);
  float var = (lq[0] + lq[1]) * (1.f / 512.f) - mu * mu;
  float rs = rsqrtf(var + BN_EPS);
  float4 gg = *(const float4*)(g + t * 4);
  float4 bb = *(const float4*)(b + t * 4);
  ushort4 hv;
  ((us*)&hv)[0] = f2bs(gg.x * (v0 - mu) * rs + bb.x);
  ((us*)&hv)[1] = f2bs(gg.y * (v1 - mu) * rs + bb.y);
  ((us*)&hv)[2] = f2bs(gg.z * (v2 - mu) * rs + bb.z);
  ((us*)&hv)[3] = f2bs(gg.w * (v3 - mu) * rs + bb.w);
  *(ushort4*)(hb + (long)r * 512 + t * 4) = hv;
}

// ---------------- head ------------------------------------------------------
__global__ void zerof(float* __restrict__ p, int n) {
  int i = blockIdx.x * 256 + threadIdx.x;
  if (i < n) p[i] = 0.f;
}

__global__ __launch_bounds__(320) void final_head(
    const float* __restrict__ feat, const float* __restrict__ bf_,
    const float* __restrict__ action, const float* __restrict__ Wfin,
    const float* __restrict__ bfin, float* __restrict__ out) {
  int t = threadIdx.x;
  int b = t & 63, o = t >> 6;
  float acc = bfin[o];
  for (int j = 0; j < 32; ++j) acc += (feat[b * 32 + j] + bf_[j]) * Wfin[j * 5 + o];
  for (int j = 0; j < 8; ++j) acc += action[b * 8 + j] * Wfin[(32 + j) * 5 + o];
  out[b * 5 + o] = acc;
}

// ---------------- host ------------------------------------------------------
extern "C" void kernel_launch(void* const* d_in, const int* in_sizes, int n_in,
                              void* d_out, int out_size, void* d_ws,
                              size_t ws_size, hipStream_t stream) {
  const float* state = (const float*)d_in[0];
  const float* action = (const float*)d_in[1];
  const float* pes = (const float*)d_in[2];
  const float* W_emb = (const float*)d_in[3];
  const float* b_emb = (const float*)d_in[4];
  const float* Wq = (const float*)d_in[5];
  const float* bq = (const float*)d_in[6];
  const float* Wk = (const float*)d_in[7];
  const float* bk = (const float*)d_in[8];
  const float* Wv = (const float*)d_in[9];
  const float* bv = (const float*)d_in[10];
  const float* Wo = (const float*)d_in[11];
  const float* bo = (const float*)d_in[12];
  const float* bn_g = (const float*)d_in[13];
  const float* bn_b = (const float*)d_in[14];
  const float* W1 = (const float*)d_in[15];
  const float* b1 = (const float*)d_in[16];
  const float* W2 = (const float*)d_in[17];
  const float* b2 = (const float*)d_in[18];
  const float* ln_g = (const float*)d_in[19];
  const float* ln_b = (const float*)d_in[20];
  const float* Wf = (const float*)d_in[21];
  const float* bf_ = (const float*)d_in[22];
  const float* Wfin = (const float*)d_in[23];
  const float* bfin = (const float*)d_in[24];
  float* out = (float*)d_out;
  (void)in_sizes; (void)n_in; (void)out_size;

  char* wp = (char*)d_ws;
  size_t off = 0;
  auto take = [&](size_t bytes) {
    void* p = wp + off;
    off += (bytes + 255) & ~(size_t)255;
    return p;
  };
  us* qkvT = (us*)take(6ull * 1536 * 512 * 2);
  us* WoT = (us*)take(6ull * 512 * 512 * 2);
  us* W1T = (us*)take(6ull * 2048 * 512 * 2);
  us* W2T = (us*)take(6ull * 512 * 2048 * 2);
  us* WfT = (us*)take(32ull * 131072 * 2);
  us* hb = (us*)take(16384ull * 512 * 2);
  us* ybf = (us*)take(16384ull * 512 * 2);
  us* W1s = (us*)take(2048ull * 512 * 2);
  float* bias1f = (float*)take(2048 * 4);
  us* qb_ = (us*)take(16384ull * 512 * 2);
  us* kb_ = (us*)take(16384ull * 512 * 2);
  us* vt = (us*)take(16384ull * 512 * 2);
  us* bigR4 = (us*)take(33554432ull * 2);
  float* gsum = (float*)take(512 * 4);
  float* gsumsq = (float*)take(512 * 4);
  float* feat = (float*)take(2048 * 4);
  us* ctxb = bigR4;
  us* f1 = bigR4;
  us* zbf = qb_;

  if (off > ws_size) return;

  transpose_bf16<<<dim3(16, 16, 6), 256, 0, stream>>>(Wq, qkvT, 512, 512,
                                                      262144, 786432);
  transpose_bf16<<<dim3(16, 16, 6), 256, 0, stream>>>(Wk, qkvT + 262144, 512,
                                                      512, 262144, 786432);
  transpose_bf16<<<dim3(16, 16, 6), 256, 0, stream>>>(Wv, qkvT + 524288, 512,
                                                      512, 262144, 786432);
  transpose_bf16<<<dim3(16, 16, 6), 256, 0, stream>>>(Wo, WoT, 512, 512,
                                                      262144, 262144);
  transpose_bf16<<<dim3(16, 64, 6), 256, 0, stream>>>(W1, W1T, 512, 2048,
                                                      1048576, 1048576);
  transpose_bf16<<<dim3(64, 16, 6), 256, 0, stream>>>(W2, W2T, 2048, 512,
                                                      1048576, 1048576);
  transpose_bf16<<<dim3(4096, 1, 1), 256, 0, stream>>>(Wf, WfT, 131072, 32,
                                                       0, 0);
  embed_kernel<<<2048, 256, 0, stream>>>(state, W_emb, b_emb, pes, hb);
  zerof<<<4, 256, 0, stream>>>(gsum, 1024);  // gsum+gsumsq contiguous (layer 0)

  for (int l = 0; l < 6; ++l) {
    const us* qkvTl = qkvT + (size_t)l * 786432;
    const us* WoTl = WoT + (size_t)l * 262144;
    const us* W1Tl = W1T + (size_t)l * 1048576;
    const us* W2Tl = W2T + (size_t)l * 1048576;

    // QKV on the 256x128 pipelined GEMM (grid 768 = 3 balanced rounds)
    gemm256x128<EPI_QKV><<<dim3(64, 12), 512, 0, stream>>>(
        hb, 512, qkvTl, 512, qb_, kb_, vt, 512, bq + l * 512, nullptr,
        nullptr, nullptr, bk + l * 512, bv + l * 512, 512);
    // attn v3: one block per (b,h), K/V cached in LDS
    attn_kernel<<<512, 512, 0, stream>>>(qb_, kb_, vt, ctxb);
    // Wo on the 256x128 pipelined GEMM (grid 256 = 1 round), fused
    // residual + BN batch-stats
    gemm256x128<EPI_RESID_BF16><<<dim3(64, 4), 512, 0, stream>>>(
        ctxb, 512, WoTl, 512, ybf, nullptr, nullptr, 512, bo + l * 512, hb,
        gsum, gsumsq, nullptr, nullptr, 512);
    bn_coef<<<2, 256, 0, stream>>>(gsum, gsumsq, bn_g + l * 512,
                                   bn_b + l * 512);
    fold_w1<<<512, 256, 0, stream>>>(W1Tl, gsum, gsumsq, b1 + l * 2048, W1s,
                                     bias1f);
    // FFN1 on the 256x128 pipelined GEMM (grid 1024 = 4 balanced rounds, R17)
    gemm256x128<EPI_RELU_BF16><<<dim3(64, 16), 512, 0, stream>>>(
        ybf, 512, W1s, 512, f1, nullptr, nullptr, 2048, bias1f, nullptr,
        nullptr, nullptr, nullptr, nullptr, 512);
    gemm256x128<EPI_FFN2_BF16><<<dim3(64, 4), 512, 0, stream>>>(
        f1, 2048, W2Tl, 2048, zbf, nullptr, nullptr, 512, b2 + l * 512, ybf,
        gsum, gsumsq, nullptr, nullptr, 2048);
    // ln also zeroes gsum/gsumsq for the next layer (block 0)
    ln_kernel<<<16384, 128, 0, stream>>>(zbf, ln_g + l * 512, ln_b + l * 512,
                                         hb, gsum, gsumsq);
  }

  zerof<<<8, 256, 0, stream>>>(feat, 2048);
  gemm_bt<64, 32, 32, 16, EPI_FEAT><<<dim3(1, 1, 128), 256, 0, stream>>>(
      hb, 131072, 1024, WfT, 131072, 1024, feat, 32, 1024);
  final_head<<<1, 320, 0, stream>>>(feat, bf_, action, Wfin, bfin, out);
}

// Round 18
// 1363.831 us; speedup vs baseline: 1.0403x; 1.0403x over previous
//
#include <hip/hip_runtime.h>

typedef short bf16x8 __attribute__((ext_vector_type(8)));
typedef float f32x4 __attribute__((ext_vector_type(4)));
typedef unsigned short us;

#define BN_EPS 1e-3f

// fp32 -> bf16 round-to-nearest-even (no NaN inputs in this net)
static __device__ __forceinline__ us f2bs(float x) {
  unsigned int u = __builtin_bit_cast(unsigned int, x);
  unsigned int r = (u + 0x7FFFu + ((u >> 16) & 1u)) >> 16;
  return (us)r;
}
static __device__ __forceinline__ float b2f(us v) {
  unsigned int u = (unsigned int)v << 16;
  return __builtin_bit_cast(float, u);
}

// async global->LDS, 16B per lane; LDS dest is wave-uniform base + lane*16.
static __device__ __forceinline__ void gl_lds16(const us* g, us* l) {
  __builtin_amdgcn_global_load_lds(
      (const __attribute__((address_space(1))) void*)g,
      (__attribute__((address_space(3))) void*)l, 16, 0, 0);
}

// ---------------- transpose + fp32->bf16: src [K,N] f32 -> dst [N,K] bf16 ----
__global__ __launch_bounds__(256) void transpose_bf16(
    const float* __restrict__ src, us* __restrict__ dst, int K, int N,
    long sstride, long dstride) {
  long sbs = (long)blockIdx.z * sstride;
  long sbd = (long)blockIdx.z * dstride;
  __shared__ float tile[32][33];
  int tx = threadIdx.x & 31, ty = threadIdx.x >> 5;  // 32 x 8
  int k0 = blockIdx.x * 32, n0 = blockIdx.y * 32;
  for (int i = 0; i < 32; i += 8)
    tile[ty + i][tx] = src[sbs + (long)(k0 + ty + i) * N + n0 + tx];
  __syncthreads();
  for (int i = 0; i < 32; i += 8)
    dst[sbd + (long)(n0 + ty + i) * K + k0 + tx] = f2bs(tile[tx][ty + i]);
}

// ---------------- embedding: hb = bf16(state @ Wemb + bemb + pes) -----------
__global__ __launch_bounds__(256) void embed_kernel(
    const float* __restrict__ state, const float* __restrict__ Wemb,
    const float* __restrict__ bemb, const float* __restrict__ pes,
    us* __restrict__ hb) {
  int t = threadIdx.x;
  int row0 = blockIdx.x * 8;
  __shared__ float st[8][64];
  {
    int i = t;
    st[i >> 6][i & 63] = state[(long)row0 * 64 + i];
    i += 256;
    st[i >> 6][i & 63] = state[(long)row0 * 64 + i];
  }
  __syncthreads();
  int c0 = t, c1 = t + 256;
  float acc0[8], acc1[8];
#pragma unroll
  for (int r = 0; r < 8; ++r) { acc0[r] = 0.f; acc1[r] = 0.f; }
  for (int kk = 0; kk < 64; ++kk) {
    float w0 = Wemb[kk * 512 + c0], w1 = Wemb[kk * 512 + c1];
#pragma unroll
    for (int r = 0; r < 8; ++r) {
      acc0[r] += st[r][kk] * w0;
      acc1[r] += st[r][kk] * w1;
    }
  }
  float be0 = bemb[c0], be1 = bemb[c1];
#pragma unroll
  for (int r = 0; r < 8; ++r) {
    int row = row0 + r, s = row & 255;
    hb[(long)row * 512 + c0] = f2bs(acc0[r] + be0 + pes[(long)s * 512 + c0]);
    hb[(long)row * 512 + c1] = f2bs(acc1[r] + be1 + pes[(long)s * 512 + c1]);
  }
}

enum { EPI_QKV = 0, EPI_RESID_BF16 = 1, EPI_RELU_BF16 = 2, EPI_FFN2_BF16 = 3,
       EPI_FEAT = 4 };

// =============== 8-wave 256x256 pipelined GEMM (FFN1) =======================
// R18: FFN1 reverted here from the x128 template (R17 lesson: halving BN
// doubles A-panel re-reads, FETCH 24.7->38.6MB, 53.6->62us regression).
template <int EPI>
__global__ __launch_bounds__(512, 2) void gemm256(
    const us* __restrict__ A, int lda, const us* __restrict__ Bt, int ldb,
    void* __restrict__ Cout, int ldc, const float* __restrict__ bias, int K) {
  const int tid = threadIdx.x;
  const int w = tid >> 6, l = tid & 63;
  const int wr = w >> 2, wc = w & 3;
  const int lr = l & 15, lh = l >> 4;
  const long m0 = (long)blockIdx.x * 256;
  const long n0 = (long)blockIdx.y * 256;
  const int KC = K >> 5;
  __shared__ __align__(16) us sh[4 * 16384];  // 4 slots x 32KB
  const int o = tid * 16;
  const int lg = o ^ ((o >> 2) & 0x30);
  const int sr = lg >> 6;
  const int sc = (lg & 63) >> 1;
  const int pb = lr * 32 + ((lh * 8) ^ ((lr & 3) << 3));
  const us* Asl = sh + wr * 4096 + pb;
  const us* Bsl = sh + 8192 + (wc >> 1) * 4096 + (wc & 1) * 2048 + pb;

  for (int j = 0; j < 3; ++j) {
    us* slot = sh + j * 16384;
    gl_lds16(A + (m0 + sr) * lda + j * 32 + sc, slot + tid * 8);
    gl_lds16(A + (m0 + 128 + sr) * lda + j * 32 + sc, slot + 4096 + tid * 8);
    gl_lds16(Bt + (n0 + sr) * ldb + j * 32 + sc, slot + 8192 + tid * 8);
    gl_lds16(Bt + (n0 + 128 + sr) * ldb + j * 32 + sc, slot + 12288 + tid * 8);
  }
  asm volatile("s_waitcnt vmcnt(8)" ::: "memory");
  __builtin_amdgcn_s_barrier();

  f32x4 acc[8][4] = {};
  for (int c = 0; c < KC; ++c) {
    const int soff = (c & 3) * 16384;
    const bool st = (c + 3) < KC;
    us* nslot = sh + ((c + 3) & 3) * 16384;
    const int nk = (c + 3) * 32;
    if (st) {
      gl_lds16(A + (m0 + sr) * lda + nk + sc, nslot + tid * 8);
      gl_lds16(A + (m0 + 128 + sr) * lda + nk + sc, nslot + 4096 + tid * 8);
    }
    bf16x8 bfr[4], af[4];
#pragma unroll
    for (int ni = 0; ni < 4; ++ni)
      bfr[ni] = *(const bf16x8*)(Bsl + soff + ni * 512);
#pragma unroll
    for (int mi = 0; mi < 4; ++mi)
      af[mi] = *(const bf16x8*)(Asl + soff + mi * 512);
    __builtin_amdgcn_s_barrier();
    __builtin_amdgcn_s_setprio(1);
#pragma unroll
    for (int mi = 0; mi < 4; ++mi)
#pragma unroll
      for (int ni = 0; ni < 4; ++ni)
        acc[mi][ni] = __builtin_amdgcn_mfma_f32_16x16x32_bf16(
            af[mi], bfr[ni], acc[mi][ni], 0, 0, 0);
    __builtin_amdgcn_s_setprio(0);
    __builtin_amdgcn_s_barrier();
    if (st) {
      gl_lds16(Bt + (n0 + sr) * ldb + nk + sc, nslot + 8192 + tid * 8);
      gl_lds16(Bt + (n0 + 128 + sr) * ldb + nk + sc, nslot + 12288 + tid * 8);
    }
#pragma unroll
    for (int mi = 0; mi < 4; ++mi)
      af[mi] = *(const bf16x8*)(Asl + soff + (mi + 4) * 512);
    __builtin_amdgcn_s_barrier();
    __builtin_amdgcn_s_setprio(1);
#pragma unroll
    for (int mi = 0; mi < 4; ++mi)
#pragma unroll
      for (int ni = 0; ni < 4; ++ni)
        acc[mi + 4][ni] = __builtin_amdgcn_mfma_f32_16x16x32_bf16(
            af[mi], bfr[ni], acc[mi + 4][ni], 0, 0, 0);
    __builtin_amdgcn_s_setprio(0);
    if (c < KC - 3)
      asm volatile("s_waitcnt vmcnt(8)" ::: "memory");
    else if (c == KC - 3)
      asm volatile("s_waitcnt vmcnt(4)" ::: "memory");
    else if (c == KC - 2)
      asm volatile("s_waitcnt vmcnt(0)" ::: "memory");
    __builtin_amdgcn_s_barrier();
  }
  // epilogue: bf16 staged coalesced write (EPI_RELU_BF16)
#pragma unroll
  for (int mi = 0; mi < 8; ++mi)
#pragma unroll
    for (int ni = 0; ni < 4; ++ni) {
      const int cl = wc * 64 + ni * 16 + lr;
      const float bv_ = bias[(int)n0 + cl];
#pragma unroll
      for (int q_ = 0; q_ < 4; ++q_) {
        const int rl = wr * 128 + mi * 16 + lh * 4 + q_;
        sh[rl * 256 + cl] = f2bs(fmaxf(acc[mi][ni][q_] + bv_, 0.f));
      }
    }
  asm volatile("s_waitcnt lgkmcnt(0)" ::: "memory");
  __builtin_amdgcn_s_barrier();
  for (int i = tid; i < 8192; i += 512) {
    const int idx = i * 8;
    const int row = idx >> 8, col = idx & 255;
    *(uint4*)&((us*)Cout)[(m0 + row) * ldc + n0 + col] = *(uint4*)&sh[idx];
  }
}

// =============== 8-wave 256x128 pipelined GEMM (QKV / Wo / FFN2) ============
template <int EPI>
__global__ __launch_bounds__(512, 2) void gemm256x128(
    const us* __restrict__ A, int lda, const us* __restrict__ Bt, int ldb,
    us* __restrict__ Cout, us* __restrict__ C2, us* __restrict__ C3, int ldc,
    const float* __restrict__ bias, const us* __restrict__ resid,
    float* __restrict__ gsum, float* __restrict__ gsumsq,
    const float* __restrict__ gamma, const float* __restrict__ beta, int K) {
  const int tid = threadIdx.x;
  const int w = tid >> 6, l = tid & 63;
  const int wr = w >> 1, wc = w & 1;
  const int lr = l & 15, lh = l >> 4;
  const long m0 = (long)blockIdx.x * 256;
  const long n0 = (long)blockIdx.y * 128;
  const int KC = K >> 5;
  __shared__ __align__(16) us sh[4 * 12288];  // 4 slots x 24KB = 96KB
  const int o = tid * 16;
  const int lg = o ^ ((o >> 2) & 0x30);
  const int sr = lg >> 6;
  const int sc = (lg & 63) >> 1;
  const int pb = lr * 32 + ((lh * 8) ^ ((lr & 3) << 3));
  const us* Asl = sh + wr * 2048 + pb;          // A: [0, 8192) us
  const us* Bsl = sh + 8192 + wc * 2048 + pb;   // B: [8192, 12288) us

  for (int j = 0; j < 3; ++j) {
    us* slot = sh + j * 12288;
    gl_lds16(A + (m0 + sr) * lda + j * 32 + sc, slot + tid * 8);
    gl_lds16(A + (m0 + 128 + sr) * lda + j * 32 + sc, slot + 4096 + tid * 8);
    gl_lds16(Bt + (n0 + sr) * ldb + j * 32 + sc, slot + 8192 + tid * 8);
  }
  asm volatile("s_waitcnt vmcnt(6)" ::: "memory");  // chunk 0's 3 loads done
  __builtin_amdgcn_s_barrier();

  f32x4 acc[4][4] = {};
  for (int c = 0; c < KC; ++c) {
    const int soff = (c & 3) * 12288;
    const bool st = (c + 3) < KC;
    us* nslot = sh + ((c + 3) & 3) * 12288;
    const int nk = (c + 3) * 32;
    if (st) {
      gl_lds16(A + (m0 + sr) * lda + nk + sc, nslot + tid * 8);
      gl_lds16(A + (m0 + 128 + sr) * lda + nk + sc, nslot + 4096 + tid * 8);
    }
    bf16x8 bfr[4], af[2];
#pragma unroll
    for (int ni = 0; ni < 4; ++ni)
      bfr[ni] = *(const bf16x8*)(Bsl + soff + ni * 512);
#pragma unroll
    for (int mi = 0; mi < 2; ++mi)
      af[mi] = *(const bf16x8*)(Asl + soff + mi * 512);
    __builtin_amdgcn_s_barrier();
    __builtin_amdgcn_s_setprio(1);
#pragma unroll
    for (int mi = 0; mi < 2; ++mi)
#pragma unroll
      for (int ni = 0; ni < 4; ++ni)
        acc[mi][ni] = __builtin_amdgcn_mfma_f32_16x16x32_bf16(
            af[mi], bfr[ni], acc[mi][ni], 0, 0, 0);
    __builtin_amdgcn_s_setprio(0);
    __builtin_amdgcn_s_barrier();
    if (st) {
      gl_lds16(Bt + (n0 + sr) * ldb + nk + sc, nslot + 8192 + tid * 8);
    }
#pragma unroll
    for (int mi = 0; mi < 2; ++mi)
      af[mi] = *(const bf16x8*)(Asl + soff + (mi + 2) * 512);
    __builtin_amdgcn_s_barrier();
    __builtin_amdgcn_s_setprio(1);
#pragma unroll
    for (int mi = 0; mi < 2; ++mi)
#pragma unroll
      for (int ni = 0; ni < 4; ++ni)
        acc[mi + 2][ni] = __builtin_amdgcn_mfma_f32_16x16x32_bf16(
            af[mi], bfr[ni], acc[mi + 2][ni], 0, 0, 0);
    __builtin_amdgcn_s_setprio(0);
    if (c < KC - 3)
      asm volatile("s_waitcnt vmcnt(6)" ::: "memory");
    else if (c == KC - 3)
      asm volatile("s_waitcnt vmcnt(3)" ::: "memory");
    else if (c == KC - 2)
      asm volatile("s_waitcnt vmcnt(0)" ::: "memory");
    __builtin_amdgcn_s_barrier();
  }

  if constexpr (EPI == EPI_QKV) {
    const int seg = (int)(n0 >> 9);  // block-uniform
    const int nc0 = (int)(n0 & 511);
    if (seg == 2) {
      // V^T: 4 consecutive s-rows contiguous -> ushort4 register path
#pragma unroll
      for (int mi = 0; mi < 4; ++mi)
#pragma unroll
        for (int ni = 0; ni < 4; ++ni) {
          const int segc = nc0 + wc * 64 + ni * 16 + lr;
          const float bv_ = beta[segc];
          ushort4 pv;
#pragma unroll
          for (int q_ = 0; q_ < 4; ++q_)
            ((us*)&pv)[q_] = f2bs(acc[mi][ni][q_] + bv_);
          const long row0g = m0 + wr * 64 + mi * 16 + lh * 4;
          const long oo =
              (((row0g >> 8) * 8 + (segc >> 6)) * 64 + (segc & 63)) * 256 +
              (row0g & 255);
          *(ushort4*)&C3[oo] = pv;
        }
    } else {
      // q/k: stage C-tile [256][128] in sh, coalesced write
#pragma unroll
      for (int mi = 0; mi < 4; ++mi)
#pragma unroll
        for (int ni = 0; ni < 4; ++ni) {
          const int cl = wc * 64 + ni * 16 + lr;
          const float bv_ = seg == 0 ? bias[nc0 + cl] : gamma[nc0 + cl];
#pragma unroll
          for (int q_ = 0; q_ < 4; ++q_) {
            const int rl = wr * 64 + mi * 16 + lh * 4 + q_;
            sh[rl * 128 + cl] = f2bs(acc[mi][ni][q_] + bv_);
          }
        }
      asm volatile("s_waitcnt lgkmcnt(0)" ::: "memory");
      __builtin_amdgcn_s_barrier();
      us* dstp = seg == 0 ? Cout : C2;
      for (int i = tid; i < 4096; i += 512) {
        const int idx = i * 8;
        const int row = idx >> 7, col = idx & 127;
        *(uint4*)&dstp[(m0 + row) * 512 + nc0 + col] = *(uint4*)&sh[idx];
      }
    }
  } else if constexpr (EPI == EPI_RESID_BF16) {
    // y = acc + bias + resid; fused BN-stats (shfl reduce + global atomics)
    float cs[4] = {}, cq[4] = {};
#pragma unroll
    for (int mi = 0; mi < 4; ++mi)
#pragma unroll
      for (int ni = 0; ni < 4; ++ni) {
        const int cl = wc * 64 + ni * 16 + lr;
        const int col = (int)n0 + cl;
        const float bv_ = bias[col];
#pragma unroll
        for (int q_ = 0; q_ < 4; ++q_) {
          const int rl = wr * 64 + mi * 16 + lh * 4 + q_;
          float v = acc[mi][ni][q_] + bv_ + b2f(resid[(m0 + rl) * ldc + col]);
          cs[ni] += v;
          cq[ni] += v * v;
          sh[rl * 128 + cl] = f2bs(v);
        }
      }
#pragma unroll
    for (int ni = 0; ni < 4; ++ni) {
      float s = cs[ni], qv = cq[ni];
      s += __shfl_xor(s, 16);
      qv += __shfl_xor(qv, 16);
      s += __shfl_xor(s, 32);
      qv += __shfl_xor(qv, 32);
      if (lh == 0) {
        const int col = (int)n0 + wc * 64 + ni * 16 + lr;
        atomicAdd(&gsum[col], s);
        atomicAdd(&gsumsq[col], qv);
      }
    }
    asm volatile("s_waitcnt lgkmcnt(0)" ::: "memory");
    __builtin_amdgcn_s_barrier();
    for (int i = tid; i < 4096; i += 512) {
      const int idx = i * 8;
      const int row = idx >> 7, col = idx & 127;
      *(uint4*)&Cout[(m0 + row) * ldc + n0 + col] = *(uint4*)&sh[idx];
    }
  } else {  // EPI_FFN2_BF16: z = (a*y+b) + acc + bias  (a,b from bnA/bnB)
#pragma unroll
    for (int mi = 0; mi < 4; ++mi)
#pragma unroll
      for (int ni = 0; ni < 4; ++ni) {
        const int cl = wc * 64 + ni * 16 + lr;
        const int col = (int)n0 + cl;
        const float bv_ = bias[col];
        const float aa = gsum[col], bb2 = gsumsq[col];
#pragma unroll
        for (int q_ = 0; q_ < 4; ++q_) {
          const int rl = wr * 64 + mi * 16 + lh * 4 + q_;
          float ybn = b2f(resid[(m0 + rl) * ldc + col]) * aa + bb2;
          sh[rl * 128 + cl] = f2bs(ybn + acc[mi][ni][q_] + bv_);
        }
      }
    asm volatile("s_waitcnt lgkmcnt(0)" ::: "memory");
    __builtin_amdgcn_s_barrier();
    for (int i = tid; i < 4096; i += 512) {
      const int idx = i * 8;
      const int row = idx >> 7, col = idx & 127;
      *(uint4*)&Cout[(m0 + row) * ldc + n0 + col] = *(uint4*)&sh[idx];
    }
  }
}

// ---------------- generic bf16 MFMA GEMM (feat split-K only) ----------------
template <int BM, int BN, int WM, int WN, int EPI>
__global__ __launch_bounds__((BM / WM) * (BN / WN) * 64)
void gemm_bt(const us* __restrict__ A, int lda, long batchA,
             const us* __restrict__ Bt, int ldb, long batchB,
             void* __restrict__ Cout, int ldc, int K) {
  constexpr int WCols = BN / WN;
  constexpr int NT = (BM / WM) * (BN / WN) * 64;
  constexpr int NW = NT / 64;
  constexpr int MI = WM / 16, NI = WN / 16;
  constexpr int LA = BM / 8;
  constexpr int LB = BN / 8;
  const int tid = threadIdx.x;
  const int w = tid >> 6, l = tid & 63;
  const int wr = w / WCols, wc = w % WCols;
  const int lr = l & 15, lh = l >> 4;
  const int z = blockIdx.z;
  const long m0 = (long)blockIdx.x * BM;
  const long n0 = (long)blockIdx.y * BN;
  A += (long)z * batchA;
  Bt += (long)z * batchB;
  __shared__ __align__(16) us smem[BM * 64 + BN * 64];
  us* Asm = smem;
  us* Bsm = smem + BM * 64;
  const int srow = l >> 3, scol = (l & 7) << 3;
  f32x4 acc[MI][NI] = {};
  for (int kt = 0; kt < K; kt += 64) {
    __syncthreads();
    for (int j = w; j < LA; j += NW) {
      int rb = j * 8;
      gl_lds16(A + (m0 + rb + srow) * lda + kt + scol, Asm + rb * 64);
    }
    for (int j = w; j < LB; j += NW) {
      int rb = j * 8;
      gl_lds16(Bt + (n0 + rb + srow) * ldb + kt + scol, Bsm + rb * 64);
    }
    asm volatile("s_waitcnt vmcnt(0)" ::: "memory");
    __syncthreads();
#pragma unroll
    for (int kk = 0; kk < 64; kk += 32) {
      bf16x8 af[MI], bfr[NI];
#pragma unroll
      for (int mi = 0; mi < MI; ++mi)
        af[mi] = *(const bf16x8*)&Asm[(wr * WM + mi * 16 + lr) * 64 + kk + lh * 8];
#pragma unroll
      for (int ni = 0; ni < NI; ++ni)
        bfr[ni] = *(const bf16x8*)&Bsm[(wc * WN + ni * 16 + lr) * 64 + kk + lh * 8];
#pragma unroll
      for (int mi = 0; mi < MI; ++mi)
#pragma unroll
        for (int ni = 0; ni < NI; ++ni)
          acc[mi][ni] = __builtin_amdgcn_mfma_f32_16x16x32_bf16(
              af[mi], bfr[ni], acc[mi][ni], 0, 0, 0);
    }
  }
#pragma unroll
  for (int mi = 0; mi < MI; ++mi) {
#pragma unroll
    for (int ni = 0; ni < NI; ++ni) {
      const int col = (int)n0 + wc * WN + ni * 16 + lr;
#pragma unroll
      for (int q_ = 0; q_ < 4; ++q_) {
        const long row = m0 + wr * WM + mi * 16 + lh * 4 + q_;
        atomicAdd(&((float*)Cout)[row * ldc + col], acc[mi][ni][q_]);
      }
    }
  }
}

// ---------------- fused attention v3: K/V cached in LDS per (b,h) -----------
__global__ __launch_bounds__(512) void attn_kernel(
    const us* __restrict__ q, const us* __restrict__ k,
    const us* __restrict__ vt, us* __restrict__ ctx) {
  const int z = blockIdx.x;  // b*8+h
  const int b = z >> 3, hh = z & 7;
  const long qkBase = (long)b * 131072 + hh * 64;
  const int tid = threadIdx.x, w = tid >> 6, l = tid & 63;
  const int lr = l & 15, lh = l >> 4;
  const int hf = w >> 2, w2 = w & 3;  // wave-group (tile) and sub-wave
  const int qr = (w2 >> 1) * 16, qc = (w2 & 1) * 32;
  __shared__ __align__(16) us Kf[256][72];   // 36.9 KB
  __shared__ __align__(16) us Vf[64][264];   // 33.8 KB
  __shared__ __align__(16) us Qs[2][32][72];
  __shared__ __align__(16) us Pb[2][32][264];
  __shared__ float fred[2][32][2];
  const us* vb = vt + (long)z * 16384;
  for (int i = tid; i < 2048; i += 512) {
    int r = i >> 3, c = (i & 7) << 3;
    *(uint4*)&Kf[r][c] = *(const uint4*)(k + qkBase + (long)r * 512 + c);
  }
  for (int i = tid; i < 2048; i += 512) {
    int r = i >> 5, c = (i & 31) << 3;
    *(uint4*)&Vf[r][c] = *(const uint4*)(vb + (long)r * 256 + c);
  }
  const int th = tid & 255, qhf = tid >> 8;
  const int qlr = th >> 3, qlc = (th & 7) << 3;
  __syncthreads();

  for (int qi = 0; qi < 4; ++qi) {
    const int qbl = qi * 2 + qhf;
    *(uint4*)&Qs[qhf][qlr][qlc] =
        *(const uint4*)(q + qkBase + (long)(qbl * 32 + qlr) * 512 + qlc);
    __syncthreads();
    const int myqb = qi * 2 + hf;
    f32x4 sacc[4][2] = {};
#pragma unroll
    for (int skb = 0; skb < 4; ++skb)
#pragma unroll
      for (int kh = 0; kh < 2; ++kh) {
        bf16x8 aq = *(const bf16x8*)&Qs[hf][qr + lr][kh * 32 + lh * 8];
#pragma unroll
        for (int ni = 0; ni < 2; ++ni) {
          bf16x8 bkk =
              *(const bf16x8*)&Kf[skb * 64 + qc + ni * 16 + lr][kh * 32 + lh * 8];
          sacc[skb][ni] = __builtin_amdgcn_mfma_f32_16x16x32_bf16(
              aq, bkk, sacc[skb][ni], 0, 0, 0);
        }
      }
    float m0[4] = {-1e30f, -1e30f, -1e30f, -1e30f};
#pragma unroll
    for (int skb = 0; skb < 4; ++skb)
#pragma unroll
      for (int ni = 0; ni < 2; ++ni)
#pragma unroll
        for (int q_ = 0; q_ < 4; ++q_) {
          float v = sacc[skb][ni][q_] * 0.125f;
          sacc[skb][ni][q_] = v;
          m0[q_] = fmaxf(m0[q_], v);
        }
#pragma unroll
    for (int off = 1; off < 16; off <<= 1)
#pragma unroll
      for (int q_ = 0; q_ < 4; ++q_)
        m0[q_] = fmaxf(m0[q_], __shfl_xor(m0[q_], off));
    if (lr == 0) {
#pragma unroll
      for (int q_ = 0; q_ < 4; ++q_)
        fred[hf][qr + lh * 4 + q_][w2 & 1] = m0[q_];
    }
    __syncthreads();
#pragma unroll
    for (int q_ = 0; q_ < 4; ++q_) {
      int row = qr + lh * 4 + q_;
      m0[q_] = fmaxf(fred[hf][row][0], fred[hf][row][1]);
    }
    float s0[4] = {0.f, 0.f, 0.f, 0.f};
#pragma unroll
    for (int skb = 0; skb < 4; ++skb)
#pragma unroll
      for (int ni = 0; ni < 2; ++ni)
#pragma unroll
        for (int q_ = 0; q_ < 4; ++q_) {
          float e = __expf(sacc[skb][ni][q_] - m0[q_]);
          sacc[skb][ni][q_] = e;
          s0[q_] += e;
        }
#pragma unroll
    for (int off = 1; off < 16; off <<= 1)
#pragma unroll
      for (int q_ = 0; q_ < 4; ++q_) s0[q_] += __shfl_xor(s0[q_], off);
    __syncthreads();
    if (lr == 0) {
#pragma unroll
      for (int q_ = 0; q_ < 4; ++q_)
        fred[hf][qr + lh * 4 + q_][w2 & 1] = s0[q_];
    }
    __syncthreads();
#pragma unroll
    for (int q_ = 0; q_ < 4; ++q_) {
      int row = qr + lh * 4 + q_;
      s0[q_] = 1.f / (fred[hf][row][0] + fred[hf][row][1]);
    }
#pragma unroll
    for (int skb = 0; skb < 4; ++skb)
#pragma unroll
      for (int ni = 0; ni < 2; ++ni)
#pragma unroll
        for (int q_ = 0; q_ < 4; ++q_)
          Pb[hf][qr + lh * 4 + q_][skb * 64 + qc + ni * 16 + lr] =
              f2bs(sacc[skb][ni][q_] * s0[q_]);
    __syncthreads();
    f32x4 pacc[2] = {};
#pragma unroll
    for (int kc = 0; kc < 256; kc += 64)
#pragma unroll
      for (int kh = 0; kh < 2; ++kh) {
        bf16x8 ap = *(const bf16x8*)&Pb[hf][qr + lr][kc + kh * 32 + lh * 8];
#pragma unroll
        for (int ni = 0; ni < 2; ++ni) {
          bf16x8 bv2 =
              *(const bf16x8*)&Vf[qc + ni * 16 + lr][kc + kh * 32 + lh * 8];
          pacc[ni] = __builtin_amdgcn_mfma_f32_16x16x32_bf16(
              ap, bv2, pacc[ni], 0, 0, 0);
        }
      }
    const long cb2 = ((long)(b * 256 + myqb * 32)) * 512 + hh * 64;
#pragma unroll
    for (int ni = 0; ni < 2; ++ni)
#pragma unroll
      for (int q_ = 0; q_ < 4; ++q_) {
        int row = qr + lh * 4 + q_;
        int col = qc + ni * 16 + lr;
        ctx[cb2 + (long)row * 512 + col] = f2bs(pacc[ni][q_]);
      }
    __syncthreads();
  }
}

// fold_w1 + inline BN coefs (R18: bn_coef folded in; block 0 also publishes
// (a,b) to bnA/bnB for FFN2 — separate buffers, no race with raw stats).
__global__ __launch_bounds__(256) void fold_w1(
    const us* __restrict__ W1T, const float* __restrict__ gsum,
    const float* __restrict__ gsumsq, const float* __restrict__ gamma,
    const float* __restrict__ beta, const float* __restrict__ b1,
    us* __restrict__ W1s, float* __restrict__ bias1f,
    float* __restrict__ bnA, float* __restrict__ bnB) {
  const float invN = 1.f / 16384.f;
  if (blockIdx.x == 0) {
    for (int c = threadIdx.x; c < 512; c += 256) {
      float mu = gsum[c] * invN;
      float var = gsumsq[c] * invN - mu * mu;
      float a = gamma[c] * rsqrtf(var + BN_EPS);
      bnA[c] = a;
      bnB[c] = beta[c] - mu * a;
    }
  }
  int n = blockIdx.x * 4 + (threadIdx.x >> 6);
  int l = threadIdx.x & 63;
  int k0 = l * 8;
  const us* row = W1T + (long)n * 512;
  us tmp[8], outv[8];
  *(uint4*)tmp = *(const uint4*)(row + k0);
  float dot = 0.f;
#pragma unroll
  for (int j = 0; j < 8; ++j) {
    int cj = k0 + j;
    float mu = gsum[cj] * invN;
    float var = gsumsq[cj] * invN - mu * mu;
    float a = gamma[cj] * rsqrtf(var + BN_EPS);
    float b = beta[cj] - mu * a;
    float wv = b2f(tmp[j]);
    dot += b * wv;
    outv[j] = f2bs(a * wv);
  }
  *(uint4*)(W1s + (long)n * 512 + k0) = *(uint4*)outv;
  for (int off = 32; off >= 1; off >>= 1) dot += __shfl_down(dot, off);
  if (l == 0) bias1f[n] = b1[n] + dot;
}

// ---------------- LayerNorm per row: zbf (bf16) -> hb (bf16) ----------------
// block 0 also zeroes gsum/gsumsq for the next layer's fused BN stats.
__global__ __launch_bounds__(128) void ln_kernel(
    const us* __restrict__ zin, const float* __restrict__ g,
    const float* __restrict__ b, us* __restrict__ hb,
    float* __restrict__ gsum, float* __restrict__ gsumsq) {
  int r = blockIdx.x, t = threadIdx.x;
  if (r == 0) {
    for (int i = t; i < 512; i += 128) {
      gsum[i] = 0.f;
      gsumsq[i] = 0.f;
    }
  }
  const us* zr = zin + (long)r * 512;
  ushort4 vz = *(const ushort4*)(zr + t * 4);
  float v0 = b2f(((us*)&vz)[0]), v1 = b2f(((us*)&vz)[1]);
  float v2 = b2f(((us*)&vz)[2]), v3 = b2f(((us*)&vz)[3]);
  float s = v0 + v1 + v2 + v3;
  float qs = v0 * v0 + v1 * v1 + v2 * v2 + v3 * v3;
  for (int off = 32; off >= 1; off >>= 1) {
    s += __shfl_down(s, off);
    qs += __shfl_down(qs, off);
  }
  __shared__ float ls[2], lq[2];
  if ((t & 63) == 0) {
    ls[t >> 6] = s;
    lq[t >> 6] = qs;
  }
  __syncthreads();
  float mu = (ls[0] + ls[1]) * (1.f / 512.f);
  float var = (lq[0] + lq[1]) * (1.f / 512.f) - mu * mu;
  float rs = rsqrtf(var + BN_EPS);
  float4 gg = *(const float4*)(g + t * 4);
  float4 bb = *(const float4*)(b + t * 4);
  ushort4 hv;
  ((us*)&hv)[0] = f2bs(gg.x * (v0 - mu) * rs + bb.x);
  ((us*)&hv)[1] = f2bs(gg.y * (v1 - mu) * rs + bb.y);
  ((us*)&hv)[2] = f2bs(gg.z * (v2 - mu) * rs + bb.z);
  ((us*)&hv)[3] = f2bs(gg.w * (v3 - mu) * rs + bb.w);
  *(ushort4*)(hb + (long)r * 512 + t * 4) = hv;
}

// ---------------- head ------------------------------------------------------
__global__ void zerof(float* __restrict__ p, int n) {
  int i = blockIdx.x * 256 + threadIdx.x;
  if (i < n) p[i] = 0.f;
}

__global__ __launch_bounds__(320) void final_head(
    const float* __restrict__ feat, const float* __restrict__ bf_,
    const float* __restrict__ action, const float* __restrict__ Wfin,
    const float* __restrict__ bfin, float* __restrict__ out) {
  int t = threadIdx.x;
  int b = t & 63, o = t >> 6;
  float acc = bfin[o];
  for (int j = 0; j < 32; ++j) acc += (feat[b * 32 + j] + bf_[j]) * Wfin[j * 5 + o];
  for (int j = 0; j < 8; ++j) acc += action[b * 8 + j] * Wfin[(32 + j) * 5 + o];
  out[b * 5 + o] = acc;
}

// ---------------- host ------------------------------------------------------
extern "C" void kernel_launch(void* const* d_in, const int* in_sizes, int n_in,
                              void* d_out, int out_size, void* d_ws,
                              size_t ws_size, hipStream_t stream) {
  const float* state = (const float*)d_in[0];
  const float* action = (const float*)d_in[1];
  const float* pes = (const float*)d_in[2];
  const float* W_emb = (const float*)d_in[3];
  const float* b_emb = (const float*)d_in[4];
  const float* Wq = (const float*)d_in[5];
  const float* bq = (const float*)d_in[6];
  const float* Wk = (const float*)d_in[7];
  const float* bk = (const float*)d_in[8];
  const float* Wv = (const float*)d_in[9];
  const float* bv = (const float*)d_in[10];
  const float* Wo = (const float*)d_in[11];
  const float* bo = (const float*)d_in[12];
  const float* bn_g = (const float*)d_in[13];
  const float* bn_b = (const float*)d_in[14];
  const float* W1 = (const float*)d_in[15];
  const float* b1 = (const float*)d_in[16];
  const float* W2 = (const float*)d_in[17];
  const float* b2 = (const float*)d_in[18];
  const float* ln_g = (const float*)d_in[19];
  const float* ln_b = (const float*)d_in[20];
  const float* Wf = (const float*)d_in[21];
  const float* bf_ = (const float*)d_in[22];
  const float* Wfin = (const float*)d_in[23];
  const float* bfin = (const float*)d_in[24];
  float* out = (float*)d_out;
  (void)in_sizes; (void)n_in; (void)out_size;

  char* wp = (char*)d_ws;
  size_t off = 0;
  auto take = [&](size_t bytes) {
    void* p = wp + off;
    off += (bytes + 255) & ~(size_t)255;
    return p;
  };
  us* qkvT = (us*)take(6ull * 1536 * 512 * 2);
  us* WoT = (us*)take(6ull * 512 * 512 * 2);
  us* W1T = (us*)take(6ull * 2048 * 512 * 2);
  us* W2T = (us*)take(6ull * 512 * 2048 * 2);
  us* WfT = (us*)take(32ull * 131072 * 2);
  us* hb = (us*)take(16384ull * 512 * 2);
  us* ybf = (us*)take(16384ull * 512 * 2);
  us* W1s = (us*)take(2048ull * 512 * 2);
  float* bias1f = (float*)take(2048 * 4);
  us* qb_ = (us*)take(16384ull * 512 * 2);
  us* kb_ = (us*)take(16384ull * 512 * 2);
  us* vt = (us*)take(16384ull * 512 * 2);
  us* bigR4 = (us*)take(33554432ull * 2);
  float* gsum = (float*)take(512 * 4);
  float* gsumsq = (float*)take(512 * 4);
  float* bnA = (float*)take(512 * 4);
  float* bnB = (float*)take(512 * 4);
  float* feat = (float*)take(2048 * 4);
  us* ctxb = bigR4;
  us* f1 = bigR4;
  us* zbf = qb_;

  if (off > ws_size) return;

  transpose_bf16<<<dim3(16, 16, 6), 256, 0, stream>>>(Wq, qkvT, 512, 512,
                                                      262144, 786432);
  transpose_bf16<<<dim3(16, 16, 6), 256, 0, stream>>>(Wk, qkvT + 262144, 512,
                                                      512, 262144, 786432);
  transpose_bf16<<<dim3(16, 16, 6), 256, 0, stream>>>(Wv, qkvT + 524288, 512,
                                                      512, 262144, 786432);
  transpose_bf16<<<dim3(16, 16, 6), 256, 0, stream>>>(Wo, WoT, 512, 512,
                                                      262144, 262144);
  transpose_bf16<<<dim3(16, 64, 6), 256, 0, stream>>>(W1, W1T, 512, 2048,
                                                      1048576, 1048576);
  transpose_bf16<<<dim3(64, 16, 6), 256, 0, stream>>>(W2, W2T, 2048, 512,
                                                      1048576, 1048576);
  transpose_bf16<<<dim3(4096, 1, 1), 256, 0, stream>>>(Wf, WfT, 131072, 32,
                                                       0, 0);
  embed_kernel<<<2048, 256, 0, stream>>>(state, W_emb, b_emb, pes, hb);
  zerof<<<4, 256, 0, stream>>>(gsum, 1024);  // gsum+gsumsq contiguous (layer 0)

  for (int l = 0; l < 6; ++l) {
    const us* qkvTl = qkvT + (size_t)l * 786432;
    const us* WoTl = WoT + (size_t)l * 262144;
    const us* W1Tl = W1T + (size_t)l * 1048576;
    const us* W2Tl = W2T + (size_t)l * 1048576;

    // QKV on the 256x128 pipelined GEMM (grid 768 = 3 balanced rounds)
    gemm256x128<EPI_QKV><<<dim3(64, 12), 512, 0, stream>>>(
        hb, 512, qkvTl, 512, qb_, kb_, vt, 512, bq + l * 512, nullptr,
        nullptr, nullptr, bk + l * 512, bv + l * 512, 512);
    // attn v3: one block per (b,h), K/V cached in LDS
    attn_kernel<<<512, 512, 0, stream>>>(qb_, kb_, vt, ctxb);
    // Wo on the 256x128 pipelined GEMM (grid 256 = 1 round), fused
    // residual + BN batch-stats
    gemm256x128<EPI_RESID_BF16><<<dim3(64, 4), 512, 0, stream>>>(
        ctxb, 512, WoTl, 512, ybf, nullptr, nullptr, 512, bo + l * 512, hb,
        gsum, gsumsq, nullptr, nullptr, 512);
    // fold BN into W1 (bn_coef inlined; block 0 publishes bnA/bnB for FFN2)
    fold_w1<<<512, 256, 0, stream>>>(W1Tl, gsum, gsumsq, bn_g + l * 512,
                                     bn_b + l * 512, b1 + l * 2048, W1s,
                                     bias1f, bnA, bnB);
    // FFN1 on the 256x256 pipelined GEMM (R18 revert: x128 doubled A
    // re-reads, FETCH 24.7->38.6MB, 53.6->62us)
    gemm256<EPI_RELU_BF16><<<dim3(64, 8), 512, 0, stream>>>(
        ybf, 512, W1s, 512, f1, 2048, bias1f, 512);
    gemm256x128<EPI_FFN2_BF16><<<dim3(64, 4), 512, 0, stream>>>(
        f1, 2048, W2Tl, 2048, zbf, nullptr, nullptr, 512, b2 + l * 512, ybf,
        bnA, bnB, nullptr, nullptr, 2048);
    // ln also zeroes gsum/gsumsq for the next layer (block 0)
    ln_kernel<<<16384, 128, 0, stream>>>(zbf, ln_g + l * 512, ln_b + l * 512,
                                         hb, gsum, gsumsq);
  }

  zerof<<<8, 256, 0, stream>>>(feat, 2048);
  gemm_bt<64, 32, 32, 16, EPI_FEAT><<<dim3(1, 1, 128), 256, 0, stream>>>(
      hb, 131072, 1024, WfT, 131072, 1024, feat, 32, 1024);
  final_head<<<1, 320, 0, stream>>>(feat, bf_, action, Wfin, bfin, out);
}

// Round 19
// 1332.959 us; speedup vs baseline: 1.0644x; 1.0232x over previous
//
#include <hip/hip_runtime.h>

typedef short bf16x8 __attribute__((ext_vector_type(8)));
typedef float f32x4 __attribute__((ext_vector_type(4)));
typedef unsigned short us;

#define BN_EPS 1e-3f

// fp32 -> bf16 round-to-nearest-even (no NaN inputs in this net)
static __device__ __forceinline__ us f2bs(float x) {
  unsigned int u = __builtin_bit_cast(unsigned int, x);
  unsigned int r = (u + 0x7FFFu + ((u >> 16) & 1u)) >> 16;
  return (us)r;
}
static __device__ __forceinline__ float b2f(us v) {
  unsigned int u = (unsigned int)v << 16;
  return __builtin_bit_cast(float, u);
}

// async global->LDS, 16B per lane; LDS dest is wave-uniform base + lane*16.
static __device__ __forceinline__ void gl_lds16(const us* g, us* l) {
  __builtin_amdgcn_global_load_lds(
      (const __attribute__((address_space(1))) void*)g,
      (__attribute__((address_space(3))) void*)l, 16, 0, 0);
}

// ---------------- transpose + fp32->bf16: src [K,N] f32 -> dst [N,K] bf16 ----
__global__ __launch_bounds__(256) void transpose_bf16(
    const float* __restrict__ src, us* __restrict__ dst, int K, int N,
    long sstride, long dstride) {
  long sbs = (long)blockIdx.z * sstride;
  long sbd = (long)blockIdx.z * dstride;
  __shared__ float tile[32][33];
  int tx = threadIdx.x & 31, ty = threadIdx.x >> 5;  // 32 x 8
  int k0 = blockIdx.x * 32, n0 = blockIdx.y * 32;
  for (int i = 0; i < 32; i += 8)
    tile[ty + i][tx] = src[sbs + (long)(k0 + ty + i) * N + n0 + tx];
  __syncthreads();
  for (int i = 0; i < 32; i += 8)
    dst[sbd + (long)(n0 + ty + i) * K + k0 + tx] = f2bs(tile[tx][ty + i]);
}

// ---------------- embedding: hb = bf16(state @ Wemb + bemb + pes) -----------
__global__ __launch_bounds__(256) void embed_kernel(
    const float* __restrict__ state, const float* __restrict__ Wemb,
    const float* __restrict__ bemb, const float* __restrict__ pes,
    us* __restrict__ hb) {
  int t = threadIdx.x;
  int row0 = blockIdx.x * 8;
  __shared__ float st[8][64];
  {
    int i = t;
    st[i >> 6][i & 63] = state[(long)row0 * 64 + i];
    i += 256;
    st[i >> 6][i & 63] = state[(long)row0 * 64 + i];
  }
  __syncthreads();
  int c0 = t, c1 = t + 256;
  float acc0[8], acc1[8];
#pragma unroll
  for (int r = 0; r < 8; ++r) { acc0[r] = 0.f; acc1[r] = 0.f; }
  for (int kk = 0; kk < 64; ++kk) {
    float w0 = Wemb[kk * 512 + c0], w1 = Wemb[kk * 512 + c1];
#pragma unroll
    for (int r = 0; r < 8; ++r) {
      acc0[r] += st[r][kk] * w0;
      acc1[r] += st[r][kk] * w1;
    }
  }
  float be0 = bemb[c0], be1 = bemb[c1];
#pragma unroll
  for (int r = 0; r < 8; ++r) {
    int row = row0 + r, s = row & 255;
    hb[(long)row * 512 + c0] = f2bs(acc0[r] + be0 + pes[(long)s * 512 + c0]);
    hb[(long)row * 512 + c1] = f2bs(acc1[r] + be1 + pes[(long)s * 512 + c1]);
  }
}

enum { EPI_QKV = 0, EPI_RESID_BF16 = 1, EPI_RELU_BF16 = 2, EPI_FFN2_BF16 = 3,
       EPI_FEAT = 4 };

// R19 swizzle: g(r) = (r>>1)&3 on 16B col-blocks. Fragment reads now hit 8
// DISTINCT bank-quads per 8-lane group (was 4 quads x2 with g(r)=r&3):
// quad(lr,lh) = (4*lr + lh^g) mod 8 -> {0,4,1,5,2,6,3,7} for lh=0. Store
// source uses the same involution: lg = o ^ (((o>>7)&3)<<4).

// =============== 8-wave 256x256 pipelined GEMM (FFN1) =======================
template <int EPI>
__global__ __launch_bounds__(512, 2) void gemm256(
    const us* __restrict__ A, int lda, const us* __restrict__ Bt, int ldb,
    void* __restrict__ Cout, int ldc, const float* __restrict__ bias, int K) {
  const int tid = threadIdx.x;
  const int w = tid >> 6, l = tid & 63;
  const int wr = w >> 2, wc = w & 3;
  const int lr = l & 15, lh = l >> 4;
  const long m0 = (long)blockIdx.x * 256;
  const long n0 = (long)blockIdx.y * 256;
  const int KC = K >> 5;
  __shared__ __align__(16) us sh[4 * 16384];  // 4 slots x 32KB
  const int o = tid * 16;
  const int lg = o ^ (((o >> 7) & 3) << 4);
  const int sr = lg >> 6;
  const int sc = (lg & 63) >> 1;
  const int pb = lr * 32 + ((lh * 8) ^ (((lr >> 1) & 3) << 3));
  const us* Asl = sh + wr * 4096 + pb;
  const us* Bsl = sh + 8192 + (wc >> 1) * 4096 + (wc & 1) * 2048 + pb;

  for (int j = 0; j < 3; ++j) {
    us* slot = sh + j * 16384;
    gl_lds16(A + (m0 + sr) * lda + j * 32 + sc, slot + tid * 8);
    gl_lds16(A + (m0 + 128 + sr) * lda + j * 32 + sc, slot + 4096 + tid * 8);
    gl_lds16(Bt + (n0 + sr) * ldb + j * 32 + sc, slot + 8192 + tid * 8);
    gl_lds16(Bt + (n0 + 128 + sr) * ldb + j * 32 + sc, slot + 12288 + tid * 8);
  }
  asm volatile("s_waitcnt vmcnt(8)" ::: "memory");
  __builtin_amdgcn_s_barrier();

  f32x4 acc[8][4] = {};
  for (int c = 0; c < KC; ++c) {
    const int soff = (c & 3) * 16384;
    const bool st = (c + 3) < KC;
    us* nslot = sh + ((c + 3) & 3) * 16384;
    const int nk = (c + 3) * 32;
    if (st) {
      gl_lds16(A + (m0 + sr) * lda + nk + sc, nslot + tid * 8);
      gl_lds16(A + (m0 + 128 + sr) * lda + nk + sc, nslot + 4096 + tid * 8);
    }
    bf16x8 bfr[4], af[4];
#pragma unroll
    for (int ni = 0; ni < 4; ++ni)
      bfr[ni] = *(const bf16x8*)(Bsl + soff + ni * 512);
#pragma unroll
    for (int mi = 0; mi < 4; ++mi)
      af[mi] = *(const bf16x8*)(Asl + soff + mi * 512);
    __builtin_amdgcn_s_barrier();
    __builtin_amdgcn_s_setprio(1);
#pragma unroll
    for (int mi = 0; mi < 4; ++mi)
#pragma unroll
      for (int ni = 0; ni < 4; ++ni)
        acc[mi][ni] = __builtin_amdgcn_mfma_f32_16x16x32_bf16(
            af[mi], bfr[ni], acc[mi][ni], 0, 0, 0);
    __builtin_amdgcn_s_setprio(0);
    __builtin_amdgcn_s_barrier();
    if (st) {
      gl_lds16(Bt + (n0 + sr) * ldb + nk + sc, nslot + 8192 + tid * 8);
      gl_lds16(Bt + (n0 + 128 + sr) * ldb + nk + sc, nslot + 12288 + tid * 8);
    }
#pragma unroll
    for (int mi = 0; mi < 4; ++mi)
      af[mi] = *(const bf16x8*)(Asl + soff + (mi + 4) * 512);
    __builtin_amdgcn_s_barrier();
    __builtin_amdgcn_s_setprio(1);
#pragma unroll
    for (int mi = 0; mi < 4; ++mi)
#pragma unroll
      for (int ni = 0; ni < 4; ++ni)
        acc[mi + 4][ni] = __builtin_amdgcn_mfma_f32_16x16x32_bf16(
            af[mi], bfr[ni], acc[mi + 4][ni], 0, 0, 0);
    __builtin_amdgcn_s_setprio(0);
    if (c < KC - 3)
      asm volatile("s_waitcnt vmcnt(8)" ::: "memory");
    else if (c == KC - 3)
      asm volatile("s_waitcnt vmcnt(4)" ::: "memory");
    else if (c == KC - 2)
      asm volatile("s_waitcnt vmcnt(0)" ::: "memory");
    __builtin_amdgcn_s_barrier();
  }
  // epilogue: bf16 staged coalesced write (EPI_RELU_BF16)
#pragma unroll
  for (int mi = 0; mi < 8; ++mi)
#pragma unroll
    for (int ni = 0; ni < 4; ++ni) {
      const int cl = wc * 64 + ni * 16 + lr;
      const float bv_ = bias[(int)n0 + cl];
#pragma unroll
      for (int q_ = 0; q_ < 4; ++q_) {
        const int rl = wr * 128 + mi * 16 + lh * 4 + q_;
        sh[rl * 256 + cl] = f2bs(fmaxf(acc[mi][ni][q_] + bv_, 0.f));
      }
    }
  asm volatile("s_waitcnt lgkmcnt(0)" ::: "memory");
  __builtin_amdgcn_s_barrier();
  for (int i = tid; i < 8192; i += 512) {
    const int idx = i * 8;
    const int row = idx >> 8, col = idx & 255;
    *(uint4*)&((us*)Cout)[(m0 + row) * ldc + n0 + col] = *(uint4*)&sh[idx];
  }
}

// =============== 8-wave 256x128 pipelined GEMM (QKV / Wo / FFN2) ============
template <int EPI>
__global__ __launch_bounds__(512, 2) void gemm256x128(
    const us* __restrict__ A, int lda, const us* __restrict__ Bt, int ldb,
    us* __restrict__ Cout, us* __restrict__ C2, us* __restrict__ C3, int ldc,
    const float* __restrict__ bias, const us* __restrict__ resid,
    float* __restrict__ gsum, float* __restrict__ gsumsq,
    const float* __restrict__ gamma, const float* __restrict__ beta, int K) {
  const int tid = threadIdx.x;
  const int w = tid >> 6, l = tid & 63;
  const int wr = w >> 1, wc = w & 1;
  const int lr = l & 15, lh = l >> 4;
  const long m0 = (long)blockIdx.x * 256;
  const long n0 = (long)blockIdx.y * 128;
  const int KC = K >> 5;
  __shared__ __align__(16) us sh[4 * 12288];  // 4 slots x 24KB = 96KB
  const int o = tid * 16;
  const int lg = o ^ (((o >> 7) & 3) << 4);
  const int sr = lg >> 6;
  const int sc = (lg & 63) >> 1;
  const int pb = lr * 32 + ((lh * 8) ^ (((lr >> 1) & 3) << 3));
  const us* Asl = sh + wr * 2048 + pb;          // A: [0, 8192) us
  const us* Bsl = sh + 8192 + wc * 2048 + pb;   // B: [8192, 12288) us

  for (int j = 0; j < 3; ++j) {
    us* slot = sh + j * 12288;
    gl_lds16(A + (m0 + sr) * lda + j * 32 + sc, slot + tid * 8);
    gl_lds16(A + (m0 + 128 + sr) * lda + j * 32 + sc, slot + 4096 + tid * 8);
    gl_lds16(Bt + (n0 + sr) * ldb + j * 32 + sc, slot + 8192 + tid * 8);
  }
  asm volatile("s_waitcnt vmcnt(6)" ::: "memory");  // chunk 0's 3 loads done
  __builtin_amdgcn_s_barrier();

  f32x4 acc[4][4] = {};
  for (int c = 0; c < KC; ++c) {
    const int soff = (c & 3) * 12288;
    const bool st = (c + 3) < KC;
    us* nslot = sh + ((c + 3) & 3) * 12288;
    const int nk = (c + 3) * 32;
    if (st) {
      gl_lds16(A + (m0 + sr) * lda + nk + sc, nslot + tid * 8);
      gl_lds16(A + (m0 + 128 + sr) * lda + nk + sc, nslot + 4096 + tid * 8);
    }
    bf16x8 bfr[4], af[2];
#pragma unroll
    for (int ni = 0; ni < 4; ++ni)
      bfr[ni] = *(const bf16x8*)(Bsl + soff + ni * 512);
#pragma unroll
    for (int mi = 0; mi < 2; ++mi)
      af[mi] = *(const bf16x8*)(Asl + soff + mi * 512);
    __builtin_amdgcn_s_barrier();
    __builtin_amdgcn_s_setprio(1);
#pragma unroll
    for (int mi = 0; mi < 2; ++mi)
#pragma unroll
      for (int ni = 0; ni < 4; ++ni)
        acc[mi][ni] = __builtin_amdgcn_mfma_f32_16x16x32_bf16(
            af[mi], bfr[ni], acc[mi][ni], 0, 0, 0);
    __builtin_amdgcn_s_setprio(0);
    __builtin_amdgcn_s_barrier();
    if (st) {
      gl_lds16(Bt + (n0 + sr) * ldb + nk + sc, nslot + 8192 + tid * 8);
    }
#pragma unroll
    for (int mi = 0; mi < 2; ++mi)
      af[mi] = *(const bf16x8*)(Asl + soff + (mi + 2) * 512);
    __builtin_amdgcn_s_barrier();
    __builtin_amdgcn_s_setprio(1);
#pragma unroll
    for (int mi = 0; mi < 2; ++mi)
#pragma unroll
      for (int ni = 0; ni < 4; ++ni)
        acc[mi + 2][ni] = __builtin_amdgcn_mfma_f32_16x16x32_bf16(
            af[mi], bfr[ni], acc[mi + 2][ni], 0, 0, 0);
    __builtin_amdgcn_s_setprio(0);
    if (c < KC - 3)
      asm volatile("s_waitcnt vmcnt(6)" ::: "memory");
    else if (c == KC - 3)
      asm volatile("s_waitcnt vmcnt(3)" ::: "memory");
    else if (c == KC - 2)
      asm volatile("s_waitcnt vmcnt(0)" ::: "memory");
    __builtin_amdgcn_s_barrier();
  }

  if constexpr (EPI == EPI_QKV) {
    const int seg = (int)(n0 >> 9);  // block-uniform
    const int nc0 = (int)(n0 & 511);
    if (seg == 2) {
      // V^T: 4 consecutive s-rows contiguous -> ushort4 register path
#pragma unroll
      for (int mi = 0; mi < 4; ++mi)
#pragma unroll
        for (int ni = 0; ni < 4; ++ni) {
          const int segc = nc0 + wc * 64 + ni * 16 + lr;
          const float bv_ = beta[segc];
          ushort4 pv;
#pragma unroll
          for (int q_ = 0; q_ < 4; ++q_)
            ((us*)&pv)[q_] = f2bs(acc[mi][ni][q_] + bv_);
          const long row0g = m0 + wr * 64 + mi * 16 + lh * 4;
          const long oo =
              (((row0g >> 8) * 8 + (segc >> 6)) * 64 + (segc & 63)) * 256 +
              (row0g & 255);
          *(ushort4*)&C3[oo] = pv;
        }
    } else {
      // q/k: stage C-tile [256][128] in sh, coalesced write
#pragma unroll
      for (int mi = 0; mi < 4; ++mi)
#pragma unroll
        for (int ni = 0; ni < 4; ++ni) {
          const int cl = wc * 64 + ni * 16 + lr;
          const float bv_ = seg == 0 ? bias[nc0 + cl] : gamma[nc0 + cl];
#pragma unroll
          for (int q_ = 0; q_ < 4; ++q_) {
            const int rl = wr * 64 + mi * 16 + lh * 4 + q_;
            sh[rl * 128 + cl] = f2bs(acc[mi][ni][q_] + bv_);
          }
        }
      asm volatile("s_waitcnt lgkmcnt(0)" ::: "memory");
      __builtin_amdgcn_s_barrier();
      us* dstp = seg == 0 ? Cout : C2;
      for (int i = tid; i < 4096; i += 512) {
        const int idx = i * 8;
        const int row = idx >> 7, col = idx & 127;
        *(uint4*)&dstp[(m0 + row) * 512 + nc0 + col] = *(uint4*)&sh[idx];
      }
    }
  } else if constexpr (EPI == EPI_RESID_BF16) {
    // y = acc + bias + resid; fused BN-stats (shfl reduce + global atomics)
    float cs[4] = {}, cq[4] = {};
#pragma unroll
    for (int mi = 0; mi < 4; ++mi)
#pragma unroll
      for (int ni = 0; ni < 4; ++ni) {
        const int cl = wc * 64 + ni * 16 + lr;
        const int col = (int)n0 + cl;
        const float bv_ = bias[col];
#pragma unroll
        for (int q_ = 0; q_ < 4; ++q_) {
          const int rl = wr * 64 + mi * 16 + lh * 4 + q_;
          float v = acc[mi][ni][q_] + bv_ + b2f(resid[(m0 + rl) * ldc + col]);
          cs[ni] += v;
          cq[ni] += v * v;
          sh[rl * 128 + cl] = f2bs(v);
        }
      }
#pragma unroll
    for (int ni = 0; ni < 4; ++ni) {
      float s = cs[ni], qv = cq[ni];
      s += __shfl_xor(s, 16);
      qv += __shfl_xor(qv, 16);
      s += __shfl_xor(s, 32);
      qv += __shfl_xor(qv, 32);
      if (lh == 0) {
        const int col = (int)n0 + wc * 64 + ni * 16 + lr;
        atomicAdd(&gsum[col], s);
        atomicAdd(&gsumsq[col], qv);
      }
    }
    asm volatile("s_waitcnt lgkmcnt(0)" ::: "memory");
    __builtin_amdgcn_s_barrier();
    for (int i = tid; i < 4096; i += 512) {
      const int idx = i * 8;
      const int row = idx >> 7, col = idx & 127;
      *(uint4*)&Cout[(m0 + row) * ldc + n0 + col] = *(uint4*)&sh[idx];
    }
  } else {  // EPI_FFN2_BF16: z = (a*y+b) + acc + bias  (a,b from bnA/bnB)
#pragma unroll
    for (int mi = 0; mi < 4; ++mi)
#pragma unroll
      for (int ni = 0; ni < 4; ++ni) {
        const int cl = wc * 64 + ni * 16 + lr;
        const int col = (int)n0 + cl;
        const float bv_ = bias[col];
        const float aa = gsum[col], bb2 = gsumsq[col];
#pragma unroll
        for (int q_ = 0; q_ < 4; ++q_) {
          const int rl = wr * 64 + mi * 16 + lh * 4 + q_;
          float ybn = b2f(resid[(m0 + rl) * ldc + col]) * aa + bb2;
          sh[rl * 128 + cl] = f2bs(ybn + acc[mi][ni][q_] + bv_);
        }
      }
    asm volatile("s_waitcnt lgkmcnt(0)" ::: "memory");
    __builtin_amdgcn_s_barrier();
    for (int i = tid; i < 4096; i += 512) {
      const int idx = i * 8;
      const int row = idx >> 7, col = idx & 127;
      *(uint4*)&Cout[(m0 + row) * ldc + n0 + col] = *(uint4*)&sh[idx];
    }
  }
}

// ---------------- generic bf16 MFMA GEMM (feat split-K only) ----------------
template <int BM, int BN, int WM, int WN, int EPI>
__global__ __launch_bounds__((BM / WM) * (BN / WN) * 64)
void gemm_bt(const us* __restrict__ A, int lda, long batchA,
             const us* __restrict__ Bt, int ldb, long batchB,
             void* __restrict__ Cout, int ldc, int K) {
  constexpr int WCols = BN / WN;
  constexpr int NT = (BM / WM) * (BN / WN) * 64;
  constexpr int NW = NT / 64;
  constexpr int MI = WM / 16, NI = WN / 16;
  constexpr int LA = BM / 8;
  constexpr int LB = BN / 8;
  const int tid = threadIdx.x;
  const int w = tid >> 6, l = tid & 63;
  const int wr = w / WCols, wc = w % WCols;
  const int lr = l & 15, lh = l >> 4;
  const int z = blockIdx.z;
  const long m0 = (long)blockIdx.x * BM;
  const long n0 = (long)blockIdx.y * BN;
  A += (long)z * batchA;
  Bt += (long)z * batchB;
  __shared__ __align__(16) us smem[BM * 64 + BN * 64];
  us* Asm = smem;
  us* Bsm = smem + BM * 64;
  const int srow = l >> 3, scol = (l & 7) << 3;
  f32x4 acc[MI][NI] = {};
  for (int kt = 0; kt < K; kt += 64) {
    __syncthreads();
    for (int j = w; j < LA; j += NW) {
      int rb = j * 8;
      gl_lds16(A + (m0 + rb + srow) * lda + kt + scol, Asm + rb * 64);
    }
    for (int j = w; j < LB; j += NW) {
      int rb = j * 8;
      gl_lds16(Bt + (n0 + rb + srow) * ldb + kt + scol, Bsm + rb * 64);
    }
    asm volatile("s_waitcnt vmcnt(0)" ::: "memory");
    __syncthreads();
#pragma unroll
    for (int kk = 0; kk < 64; kk += 32) {
      bf16x8 af[MI], bfr[NI];
#pragma unroll
      for (int mi = 0; mi < MI; ++mi)
        af[mi] = *(const bf16x8*)&Asm[(wr * WM + mi * 16 + lr) * 64 + kk + lh * 8];
#pragma unroll
      for (int ni = 0; ni < NI; ++ni)
        bfr[ni] = *(const bf16x8*)&Bsm[(wc * WN + ni * 16 + lr) * 64 + kk + lh * 8];
#pragma unroll
      for (int mi = 0; mi < MI; ++mi)
#pragma unroll
        for (int ni = 0; ni < NI; ++ni)
          acc[mi][ni] = __builtin_amdgcn_mfma_f32_16x16x32_bf16(
              af[mi], bfr[ni], acc[mi][ni], 0, 0, 0);
    }
  }
#pragma unroll
  for (int mi = 0; mi < MI; ++mi) {
#pragma unroll
    for (int ni = 0; ni < NI; ++ni) {
      const int col = (int)n0 + wc * WN + ni * 16 + lr;
#pragma unroll
      for (int q_ = 0; q_ < 4; ++q_) {
        const long row = m0 + wr * WM + mi * 16 + lh * 4 + q_;
        atomicAdd(&((float*)Cout)[row * ldc + col], acc[mi][ni][q_]);
      }
    }
  }
}

// ---------------- fused attention v3: K/V cached in LDS per (b,h) -----------
__global__ __launch_bounds__(512) void attn_kernel(
    const us* __restrict__ q, const us* __restrict__ k,
    const us* __restrict__ vt, us* __restrict__ ctx) {
  const int z = blockIdx.x;  // b*8+h
  const int b = z >> 3, hh = z & 7;
  const long qkBase = (long)b * 131072 + hh * 64;
  const int tid = threadIdx.x, w = tid >> 6, l = tid & 63;
  const int lr = l & 15, lh = l >> 4;
  const int hf = w >> 2, w2 = w & 3;  // wave-group (tile) and sub-wave
  const int qr = (w2 >> 1) * 16, qc = (w2 & 1) * 32;
  __shared__ __align__(16) us Kf[256][72];   // 36.9 KB
  __shared__ __align__(16) us Vf[64][264];   // 33.8 KB
  __shared__ __align__(16) us Qs[2][32][72];
  __shared__ __align__(16) us Pb[2][32][264];
  __shared__ float fred[2][32][2];
  const us* vb = vt + (long)z * 16384;
  for (int i = tid; i < 2048; i += 512) {
    int r = i >> 3, c = (i & 7) << 3;
    *(uint4*)&Kf[r][c] = *(const uint4*)(k + qkBase + (long)r * 512 + c);
  }
  for (int i = tid; i < 2048; i += 512) {
    int r = i >> 5, c = (i & 31) << 3;
    *(uint4*)&Vf[r][c] = *(const uint4*)(vb + (long)r * 256 + c);
  }
  const int th = tid & 255, qhf = tid >> 8;
  const int qlr = th >> 3, qlc = (th & 7) << 3;
  __syncthreads();

  for (int qi = 0; qi < 4; ++qi) {
    const int qbl = qi * 2 + qhf;
    *(uint4*)&Qs[qhf][qlr][qlc] =
        *(const uint4*)(q + qkBase + (long)(qbl * 32 + qlr) * 512 + qlc);
    __syncthreads();
    const int myqb = qi * 2 + hf;
    f32x4 sacc[4][2] = {};
#pragma unroll
    for (int skb = 0; skb < 4; ++skb)
#pragma unroll
      for (int kh = 0; kh < 2; ++kh) {
        bf16x8 aq = *(const bf16x8*)&Qs[hf][qr + lr][kh * 32 + lh * 8];
#pragma unroll
        for (int ni = 0; ni < 2; ++ni) {
          bf16x8 bkk =
              *(const bf16x8*)&Kf[skb * 64 + qc + ni * 16 + lr][kh * 32 + lh * 8];
          sacc[skb][ni] = __builtin_amdgcn_mfma_f32_16x16x32_bf16(
              aq, bkk, sacc[skb][ni], 0, 0, 0);
        }
      }
    float m0[4] = {-1e30f, -1e30f, -1e30f, -1e30f};
#pragma unroll
    for (int skb = 0; skb < 4; ++skb)
#pragma unroll
      for (int ni = 0; ni < 2; ++ni)
#pragma unroll
        for (int q_ = 0; q_ < 4; ++q_) {
          float v = sacc[skb][ni][q_] * 0.125f;
          sacc[skb][ni][q_] = v;
          m0[q_] = fmaxf(m0[q_], v);
        }
#pragma unroll
    for (int off = 1; off < 16; off <<= 1)
#pragma unroll
      for (int q_ = 0; q_ < 4; ++q_)
        m0[q_] = fmaxf(m0[q_], __shfl_xor(m0[q_], off));
    if (lr == 0) {
#pragma unroll
      for (int q_ = 0; q_ < 4; ++q_)
        fred[hf][qr + lh * 4 + q_][w2 & 1] = m0[q_];
    }
    __syncthreads();
#pragma unroll
    for (int q_ = 0; q_ < 4; ++q_) {
      int row = qr + lh * 4 + q_;
      m0[q_] = fmaxf(fred[hf][row][0], fred[hf][row][1]);
    }
    float s0[4] = {0.f, 0.f, 0.f, 0.f};
#pragma unroll
    for (int skb = 0; skb < 4; ++skb)
#pragma unroll
      for (int ni = 0; ni < 2; ++ni)
#pragma unroll
        for (int q_ = 0; q_ < 4; ++q_) {
          float e = __expf(sacc[skb][ni][q_] - m0[q_]);
          sacc[skb][ni][q_] = e;
          s0[q_] += e;
        }
#pragma unroll
    for (int off = 1; off < 16; off <<= 1)
#pragma unroll
      for (int q_ = 0; q_ < 4; ++q_) s0[q_] += __shfl_xor(s0[q_], off);
    __syncthreads();
    if (lr == 0) {
#pragma unroll
      for (int q_ = 0; q_ < 4; ++q_)
        fred[hf][qr + lh * 4 + q_][w2 & 1] = s0[q_];
    }
    __syncthreads();
#pragma unroll
    for (int q_ = 0; q_ < 4; ++q_) {
      int row = qr + lh * 4 + q_;
      s0[q_] = 1.f / (fred[hf][row][0] + fred[hf][row][1]);
    }
#pragma unroll
    for (int skb = 0; skb < 4; ++skb)
#pragma unroll
      for (int ni = 0; ni < 2; ++ni)
#pragma unroll
        for (int q_ = 0; q_ < 4; ++q_)
          Pb[hf][qr + lh * 4 + q_][skb * 64 + qc + ni * 16 + lr] =
              f2bs(sacc[skb][ni][q_] * s0[q_]);
    __syncthreads();
    f32x4 pacc[2] = {};
#pragma unroll
    for (int kc = 0; kc < 256; kc += 64)
#pragma unroll
      for (int kh = 0; kh < 2; ++kh) {
        bf16x8 ap = *(const bf16x8*)&Pb[hf][qr + lr][kc + kh * 32 + lh * 8];
#pragma unroll
        for (int ni = 0; ni < 2; ++ni) {
          bf16x8 bv2 =
              *(const bf16x8*)&Vf[qc + ni * 16 + lr][kc + kh * 32 + lh * 8];
          pacc[ni] = __builtin_amdgcn_mfma_f32_16x16x32_bf16(
              ap, bv2, pacc[ni], 0, 0, 0);
        }
      }
    const long cb2 = ((long)(b * 256 + myqb * 32)) * 512 + hh * 64;
#pragma unroll
    for (int ni = 0; ni < 2; ++ni)
#pragma unroll
      for (int q_ = 0; q_ < 4; ++q_) {
        int row = qr + lh * 4 + q_;
        int col = qc + ni * 16 + lr;
        ctx[cb2 + (long)row * 512 + col] = f2bs(pacc[ni][q_]);
      }
    __syncthreads();
  }
}

// fold_w1 + inline BN coefs (block 0 also publishes (a,b) to bnA/bnB)
__global__ __launch_bounds__(256) void fold_w1(
    const us* __restrict__ W1T, const float* __restrict__ gsum,
    const float* __restrict__ gsumsq, const float* __restrict__ gamma,
    const float* __restrict__ beta, const float* __restrict__ b1,
    us* __restrict__ W1s, float* __restrict__ bias1f,
    float* __restrict__ bnA, float* __restrict__ bnB) {
  const float invN = 1.f / 16384.f;
  if (blockIdx.x == 0) {
    for (int c = threadIdx.x; c < 512; c += 256) {
      float mu = gsum[c] * invN;
      float var = gsumsq[c] * invN - mu * mu;
      float a = gamma[c] * rsqrtf(var + BN_EPS);
      bnA[c] = a;
      bnB[c] = beta[c] - mu * a;
    }
  }
  int n = blockIdx.x * 4 + (threadIdx.x >> 6);
  int l = threadIdx.x & 63;
  int k0 = l * 8;
  const us* row = W1T + (long)n * 512;
  us tmp[8], outv[8];
  *(uint4*)tmp = *(const uint4*)(row + k0);
  float dot = 0.f;
#pragma unroll
  for (int j = 0; j < 8; ++j) {
    int cj = k0 + j;
    float mu = gsum[cj] * invN;
    float var = gsumsq[cj] * invN - mu * mu;
    float a = gamma[cj] * rsqrtf(var + BN_EPS);
    float b = beta[cj] - mu * a;
    float wv = b2f(tmp[j]);
    dot += b * wv;
    outv[j] = f2bs(a * wv);
  }
  *(uint4*)(W1s + (long)n * 512 + k0) = *(uint4*)outv;
  for (int off = 32; off >= 1; off >>= 1) dot += __shfl_down(dot, off);
  if (l == 0) bias1f[n] = b1[n] + dot;
}

// ---------------- LayerNorm per row: zbf (bf16) -> hb (bf16) ----------------
// block 0 also zeroes gsum/gsumsq for the next layer's fused BN stats.
__global__ __launch_bounds__(128) void ln_kernel(
    const us* __restrict__ zin, const float* __restrict__ g,
    const float* __restrict__ b, us* __restrict__ hb,
    float* __restrict__ gsum, float* __restrict__ gsumsq) {
  int r = blockIdx.x, t = threadIdx.x;
  if (r == 0) {
    for (int i = t; i < 512; i += 128) {
      gsum[i] = 0.f;
      gsumsq[i] = 0.f;
    }
  }
  const us* zr = zin + (long)r * 512;
  ushort4 vz = *(const ushort4*)(zr + t * 4);
  float v0 = b2f(((us*)&vz)[0]), v1 = b2f(((us*)&vz)[1]);
  float v2 = b2f(((us*)&vz)[2]), v3 = b2f(((us*)&vz)[3]);
  float s = v0 + v1 + v2 + v3;
  float qs = v0 * v0 + v1 * v1 + v2 * v2 + v3 * v3;
  for (int off = 32; off >= 1; off >>= 1) {
    s += __shfl_down(s, off);
    qs += __shfl_down(qs, off);
  }
  __shared__ float ls[2], lq[2];
  if ((t & 63) == 0) {
    ls[t >> 6] = s;
    lq[t >> 6] = qs;
  }
  __syncthreads();
  float mu = (ls[0] + ls[1]) * (1.f / 512.f);
  float var = (lq[0] + lq[1]) * (1.f / 512.f) - mu * mu;
  float rs = rsqrtf(var + BN_EPS);
  float4 gg = *(const float4*)(g + t * 4);
  float4 bb = *(const float4*)(b + t * 4);
  ushort4 hv;
  ((us*)&hv)[0] = f2bs(gg.x * (v0 - mu) * rs + bb.x);
  ((us*)&hv)[1] = f2bs(gg.y * (v1 - mu) * rs + bb.y);
  ((us*)&hv)[2] = f2bs(gg.z * (v2 - mu) * rs + bb.z);
  ((us*)&hv)[3] = f2bs(gg.w * (v3 - mu) * rs + bb.w);
  *(ushort4*)(hb + (long)r * 512 + t * 4) = hv;
}

// ---------------- head ------------------------------------------------------
__global__ void zerof(float* __restrict__ p, int n) {
  int i = blockIdx.x * 256 + threadIdx.x;
  if (i < n) p[i] = 0.f;
}

__global__ __launch_bounds__(320) void final_head(
    const float* __restrict__ feat, const float* __restrict__ bf_,
    const float* __restrict__ action, const float* __restrict__ Wfin,
    const float* __restrict__ bfin, float* __restrict__ out) {
  int t = threadIdx.x;
  int b = t & 63, o = t >> 6;
  float acc = bfin[o];
  for (int j = 0; j < 32; ++j) acc += (feat[b * 32 + j] + bf_[j]) * Wfin[j * 5 + o];
  for (int j = 0; j < 8; ++j) acc += action[b * 8 + j] * Wfin[(32 + j) * 5 + o];
  out[b * 5 + o] = acc;
}

// ---------------- host ------------------------------------------------------
extern "C" void kernel_launch(void* const* d_in, const int* in_sizes, int n_in,
                              void* d_out, int out_size, void* d_ws,
                              size_t ws_size, hipStream_t stream) {
  const float* state = (const float*)d_in[0];
  const float* action = (const float*)d_in[1];
  const float* pes = (const float*)d_in[2];
  const float* W_emb = (const float*)d_in[3];
  const float* b_emb = (const float*)d_in[4];
  const float* Wq = (const float*)d_in[5];
  const float* bq = (const float*)d_in[6];
  const float* Wk = (const float*)d_in[7];
  const float* bk = (const float*)d_in[8];
  const float* Wv = (const float*)d_in[9];
  const float* bv = (const float*)d_in[10];
  const float* Wo = (const float*)d_in[11];
  const float* bo = (const float*)d_in[12];
  const float* bn_g = (const float*)d_in[13];
  const float* bn_b = (const float*)d_in[14];
  const float* W1 = (const float*)d_in[15];
  const float* b1 = (const float*)d_in[16];
  const float* W2 = (const float*)d_in[17];
  const float* b2 = (const float*)d_in[18];
  const float* ln_g = (const float*)d_in[19];
  const float* ln_b = (const float*)d_in[20];
  const float* Wf = (const float*)d_in[21];
  const float* bf_ = (const float*)d_in[22];
  const float* Wfin = (const float*)d_in[23];
  const float* bfin = (const float*)d_in[24];
  float* out = (float*)d_out;
  (void)in_sizes; (void)n_in; (void)out_size;

  char* wp = (char*)d_ws;
  size_t off = 0;
  auto take = [&](size_t bytes) {
    void* p = wp + off;
    off += (bytes + 255) & ~(size_t)255;
    return p;
  };
  us* qkvT = (us*)take(6ull * 1536 * 512 * 2);
  us* WoT = (us*)take(6ull * 512 * 512 * 2);
  us* W1T = (us*)take(6ull * 2048 * 512 * 2);
  us* W2T = (us*)take(6ull * 512 * 2048 * 2);
  us* WfT = (us*)take(32ull * 131072 * 2);
  us* hb = (us*)take(16384ull * 512 * 2);
  us* ybf = (us*)take(16384ull * 512 * 2);
  us* W1s = (us*)take(2048ull * 512 * 2);
  float* bias1f = (float*)take(2048 * 4);
  us* qb_ = (us*)take(16384ull * 512 * 2);
  us* kb_ = (us*)take(16384ull * 512 * 2);
  us* vt = (us*)take(16384ull * 512 * 2);
  us* bigR4 = (us*)take(33554432ull * 2);
  float* gsum = (float*)take(512 * 4);
  float* gsumsq = (float*)take(512 * 4);
  float* bnA = (float*)take(512 * 4);
  float* bnB = (float*)take(512 * 4);
  float* feat = (float*)take(2048 * 4);
  us* ctxb = bigR4;
  us* f1 = bigR4;
  us* zbf = qb_;

  if (off > ws_size) return;

  transpose_bf16<<<dim3(16, 16, 6), 256, 0, stream>>>(Wq, qkvT, 512, 512,
                                                      262144, 786432);
  transpose_bf16<<<dim3(16, 16, 6), 256, 0, stream>>>(Wk, qkvT + 262144, 512,
                                                      512, 262144, 786432);
  transpose_bf16<<<dim3(16, 16, 6), 256, 0, stream>>>(Wv, qkvT + 524288, 512,
                                                      512, 262144, 786432);
  transpose_bf16<<<dim3(16, 16, 6), 256, 0, stream>>>(Wo, WoT, 512, 512,
                                                      262144, 262144);
  transpose_bf16<<<dim3(16, 64, 6), 256, 0, stream>>>(W1, W1T, 512, 2048,
                                                      1048576, 1048576);
  transpose_bf16<<<dim3(64, 16, 6), 256, 0, stream>>>(W2, W2T, 2048, 512,
                                                      1048576, 1048576);
  transpose_bf16<<<dim3(4096, 1, 1), 256, 0, stream>>>(Wf, WfT, 131072, 32,
                                                       0, 0);
  embed_kernel<<<2048, 256, 0, stream>>>(state, W_emb, b_emb, pes, hb);
  zerof<<<4, 256, 0, stream>>>(gsum, 1024);  // gsum+gsumsq contiguous (layer 0)

  for (int l = 0; l < 6; ++l) {
    const us* qkvTl = qkvT + (size_t)l * 786432;
    const us* WoTl = WoT + (size_t)l * 262144;
    const us* W1Tl = W1T + (size_t)l * 1048576;
    const us* W2Tl = W2T + (size_t)l * 1048576;

    gemm256x128<EPI_QKV><<<dim3(64, 12), 512, 0, stream>>>(
        hb, 512, qkvTl, 512, qb_, kb_, vt, 512, bq + l * 512, nullptr,
        nullptr, nullptr, bk + l * 512, bv + l * 512, 512);
    attn_kernel<<<512, 512, 0, stream>>>(qb_, kb_, vt, ctxb);
    gemm256x128<EPI_RESID_BF16><<<dim3(64, 4), 512, 0, stream>>>(
        ctxb, 512, WoTl, 512, ybf, nullptr, nullptr, 512, bo + l * 512, hb,
        gsum, gsumsq, nullptr, nullptr, 512);
    fold_w1<<<512, 256, 0, stream>>>(W1Tl, gsum, gsumsq, bn_g + l * 512,
                                     bn_b + l * 512, b1 + l * 2048, W1s,
                                     bias1f, bnA, bnB);
    gemm256<EPI_RELU_BF16><<<dim3(64, 8), 512, 0, stream>>>(
        ybf, 512, W1s, 512, f1, 2048, bias1f, 512);
    gemm256x128<EPI_FFN2_BF16><<<dim3(64, 4), 512, 0, stream>>>(
        f1, 2048, W2Tl, 2048, zbf, nullptr, nullptr, 512, b2 + l * 512, ybf,
        bnA, bnB, nullptr, nullptr, 2048);
    ln_kernel<<<16384, 128, 0, stream>>>(zbf, ln_g + l * 512, ln_b + l * 512,
                                         hb, gsum, gsumsq);
  }

  zerof<<<8, 256, 0, stream>>>(feat, 2048);
  gemm_bt<64, 32, 32, 16, EPI_FEAT><<<dim3(1, 1, 128), 256, 0, stream>>>(
      hb, 131072, 1024, WfT, 131072, 1024, feat, 32, 1024);
  final_head<<<1, 320, 0, stream>>>(feat, bf_, action, Wfin, bfin, out);
}